// Round 1
// baseline (929.403 us; speedup 1.0000x reference)
//
#include <hip/hip_runtime.h>

#define N_NODES 20000
#define HID 64
#define NSTEPS 6

__device__ __forceinline__ float softplusf_(float x) {
    return (x > 0.f) ? (x + log1pf(expf(-x))) : log1pf(expf(x));
}
__device__ __forceinline__ float sigmoidf_(float x) {
    return 1.f / (1.f + expf(-x));
}

// ---------------- CSR build ----------------

__global__ __launch_bounds__(256) void hist_kernel(const int* __restrict__ dst,
                                                   int* __restrict__ counts, int total) {
    int i = blockIdx.x * 256 + threadIdx.x;
    if (i < total) atomicAdd(&counts[dst[i]], 1);
}

__global__ __launch_bounds__(256) void scan_kernel(const int* __restrict__ counts,
                                                   int* __restrict__ row_ptr,
                                                   int* __restrict__ cursor, int n) {
    __shared__ int sums[256];
    int tid = threadIdx.x;
    int seg = (n + 255) >> 8;
    int beg = tid * seg;
    int end = min(beg + seg, n);
    int s = 0;
    for (int i = beg; i < end; ++i) s += counts[i];
    sums[tid] = s;
    __syncthreads();
    if (tid == 0) {
        int run = 0;
        for (int i = 0; i < 256; ++i) { int v = sums[i]; sums[i] = run; run += v; }
        row_ptr[n] = run;
    }
    __syncthreads();
    int off = sums[tid];
    for (int i = beg; i < end; ++i) {
        row_ptr[i] = off;
        cursor[i]  = off;
        off += counts[i];
    }
}

__global__ __launch_bounds__(256) void scatter_kernel(const int* __restrict__ esrc,
                                                      const int* __restrict__ edst,
                                                      const float* __restrict__ eval,
                                                      const float* __restrict__ g_logits,
                                                      int* __restrict__ cursor,
                                                      int2* __restrict__ entries,
                                                      int E, int total) {
    int i = blockIdx.x * 256 + threadIdx.x;
    if (i >= total) return;
    int r = i / E;  // relation index 0..5
    float g = softplusf_(g_logits[r]);
    float sign = (r & 1) ? -1.f : 1.f;  // SIGNS = (1,-1,1,-1,1,-1)
    float coef = sign * g * eval[i];
    int d = edst[i];
    int pos = atomicAdd(&cursor[d], 1);
    entries[pos] = make_int2(esrc[i], __float_as_int(coef));
}

// ---------------- transpose (generic 64-tile) ----------------
// in[r*C + c] -> out[c*R + r]
__global__ __launch_bounds__(256) void transpose64(float* __restrict__ out,
                                                   const float* __restrict__ in,
                                                   int R, int C) {
    __shared__ float tile[64][65];
    int c0 = blockIdx.x * 64, r0 = blockIdx.y * 64;
    int tx = threadIdx.x & 63, ty = threadIdx.x >> 6;
#pragma unroll
    for (int i = 0; i < 16; ++i) {
        int r = r0 + ty + i * 4;
        int c = c0 + tx;
        tile[ty + i * 4][tx] = (r < R && c < C) ? in[(size_t)r * C + c] : 0.f;
    }
    __syncthreads();
#pragma unroll
    for (int i = 0; i < 16; ++i) {
        int c = c0 + ty + i * 4;
        int r = r0 + tx;
        if (c < C && r < R) out[(size_t)c * R + r] = tile[tx][ty + i * 4];
    }
}

// ---------------- propagation step ----------------
// One wave per node; lane = batch index. h layout: [N, 64].
__global__ __launch_bounds__(256) void step_kernel(const float* __restrict__ h_in,
                                                   const float* __restrict__ h0,
                                                   float* __restrict__ h_out,
                                                   const int* __restrict__ row_ptr,
                                                   const int2* __restrict__ entries,
                                                   const float* __restrict__ alpha_logits,
                                                   int k) {
    int lane = threadIdx.x & 63;
    int node = blockIdx.x * 4 + (threadIdx.x >> 6);
    if (node >= N_NODES) return;
    // Force wave-uniform (SGPR) loop bounds -> entries[] loads become scalar
    int beg = __builtin_amdgcn_readfirstlane(row_ptr[node]);
    int end = __builtin_amdgcn_readfirstlane(row_ptr[node + 1]);
    float acc0 = 0.f, acc1 = 0.f;
    int e = beg;
    for (; e + 2 <= end; e += 2) {
        int2 a0 = entries[e];
        int2 a1 = entries[e + 1];
        acc0 = fmaf(__int_as_float(a0.y), h_in[a0.x * 64 + lane], acc0);
        acc1 = fmaf(__int_as_float(a1.y), h_in[a1.x * 64 + lane], acc1);
    }
    if (e < end) {
        int2 a0 = entries[e];
        acc0 = fmaf(__int_as_float(a0.y), h_in[a0.x * 64 + lane], acc0);
    }
    float a = sigmoidf_(alpha_logits[k]);
    int idx = node * 64 + lane;
    h_out[idx] = a * h0[idx] + (1.f - a) * (acc0 + acc1);
}

// ---------------- decode ----------------

__global__ __launch_bounds__(64) void cell_dot_kernel(float* __restrict__ cell_dot,
                                                      const int* __restrict__ cell_idx,
                                                      const float* __restrict__ cell_emb,
                                                      const float* __restrict__ W2,
                                                      const float* __restrict__ b2, int B) {
    int b = threadIdx.x;
    if (b >= B) return;
    int ci = cell_idx[b];
    float acc = b2[0];
    for (int hh = 0; hh < HID; ++hh) acc = fmaf(cell_emb[ci * HID + hh], W2[hh], acc);
    cell_dot[b] = acc;
}

__global__ __launch_bounds__(256) void decode_kernel(float* __restrict__ y,
                                                     const float* __restrict__ ctl,
                                                     const float* __restrict__ u,
                                                     const float* __restrict__ h_bn,
                                                     const float* __restrict__ W1,
                                                     const float* __restrict__ b1,
                                                     const float* __restrict__ W2,
                                                     const float* __restrict__ cell_dot,
                                                     int total) {
    __shared__ float4 pack[HID];
    __shared__ float w2s[HID];
    if (threadIdx.x < HID) {
        int hh = threadIdx.x;
        pack[hh] = make_float4(W1[0 * HID + hh], W1[1 * HID + hh], W1[2 * HID + hh], b1[hh]);
        w2s[hh] = W2[hh];
    }
    __syncthreads();
    int idx = blockIdx.x * 256 + threadIdx.x;
    if (idx >= total) return;
    int b = idx / N_NODES;
    float xc = ctl[idx], xu = u[idx], xh = h_bn[idx];
    float acc = 0.f;
#pragma unroll 8
    for (int hh = 0; hh < HID; ++hh) {
        float4 p = pack[hh];
        float t = fmaf(xc, p.x, fmaf(xu, p.y, fmaf(xh, p.z, p.w)));
        t = fmaxf(t, 0.f);
        acc = fmaf(t, w2s[hh], acc);
    }
    y[idx] = acc + cell_dot[b];
}

// ---------------- launch ----------------

extern "C" void kernel_launch(void* const* d_in, const int* in_sizes, int n_in,
                              void* d_out, int out_size, void* d_ws, size_t ws_size,
                              hipStream_t stream) {
    const float* ctl          = (const float*)d_in[0];
    const float* u_raw        = (const float*)d_in[1];
    const int*   cell_idx     = (const int*)d_in[2];
    const int*   edge_src     = (const int*)d_in[3];
    const int*   edge_dst     = (const int*)d_in[4];
    const float* edge_val     = (const float*)d_in[5];
    const float* g_logits     = (const float*)d_in[6];
    const float* alpha_logits = (const float*)d_in[7];
    const float* cell_emb     = (const float*)d_in[8];
    const float* W1           = (const float*)d_in[9];
    const float* b1           = (const float*)d_in[10];
    const float* W2           = (const float*)d_in[11];
    const float* b2           = (const float*)d_in[12];
    float* y = (float*)d_out;

    const int TE = in_sizes[3];   // 6 * E
    const int E  = TE / 6;
    const int NB = N_NODES * 64;  // h elements

    char* ws = (char*)d_ws;
    size_t off = 0;
    auto alloc = [&](size_t bytes) -> char* {
        char* p = ws + off;
        off += (bytes + 255) & ~(size_t)255;
        return p;
    };
    int*   row_ptr  = (int*)alloc((N_NODES + 1) * sizeof(int));
    int*   counts   = (int*)alloc(N_NODES * sizeof(int));
    int*   cursor   = (int*)alloc(N_NODES * sizeof(int));
    int2*  entries  = (int2*)alloc((size_t)TE * sizeof(int2));
    float* u_t      = (float*)alloc((size_t)NB * sizeof(float));
    float* hA       = (float*)alloc((size_t)NB * sizeof(float));
    float* hB       = (float*)alloc((size_t)NB * sizeof(float));
    float* h_bn     = (float*)alloc((size_t)NB * sizeof(float));
    float* cell_dot = (float*)alloc(64 * sizeof(float));

    // 1. Build combined dst-CSR with folded coefficients
    hipMemsetAsync(counts, 0, N_NODES * sizeof(int), stream);
    hist_kernel<<<(TE + 255) / 256, 256, 0, stream>>>(edge_dst, counts, TE);
    scan_kernel<<<1, 256, 0, stream>>>(counts, row_ptr, cursor, N_NODES);
    scatter_kernel<<<(TE + 255) / 256, 256, 0, stream>>>(edge_src, edge_dst, edge_val,
                                                         g_logits, cursor, entries, E, TE);

    // 2. u_raw [B,N] -> u_t [N,B]
    transpose64<<<dim3((N_NODES + 63) / 64, 1), 256, 0, stream>>>(u_t, u_raw, 64, N_NODES);

    // 3. 6 propagation steps, ping-pong
    const float* hin = u_t;
    float* hout = hA;
    for (int k = 0; k < NSTEPS; ++k) {
        hout = (k & 1) ? hB : hA;
        step_kernel<<<(N_NODES + 3) / 4, 256, 0, stream>>>(hin, u_t, hout, row_ptr,
                                                           entries, alpha_logits, k);
        hin = hout;
    }

    // 4. h_final [N,B] -> h_bn [B,N]
    transpose64<<<dim3(1, (N_NODES + 63) / 64), 256, 0, stream>>>(h_bn, hout, N_NODES, 64);

    // 5. decode
    cell_dot_kernel<<<1, 64, 0, stream>>>(cell_dot, cell_idx, cell_emb, W2, b2, 64);
    decode_kernel<<<(out_size + 255) / 256, 256, 0, stream>>>(y, ctl, u_raw, h_bn,
                                                              W1, b1, W2, cell_dot, out_size);
}

// Round 2
// 653.076 us; speedup vs baseline: 1.4231x; 1.4231x over previous
//
#include <hip/hip_runtime.h>

#define N_NODES 20000
#define HID 64
#define NSTEPS 6
#define NSLICE 8
#define SLICE_SZ (N_NODES / NSLICE)  // 2500

__device__ __forceinline__ float softplusf_(float x) {
    return (x > 0.f) ? (x + log1pf(expf(-x))) : log1pf(expf(x));
}
__device__ __forceinline__ float sigmoidf_(float x) {
    return 1.f / (1.f + expf(-x));
}

// ---------------- prep: tiny per-call constants ----------------
// gsign[r] = SIGNS[r] * softplus(g_logits[r]);  alph[k] = sigmoid(alpha_logits[k]);
// cell_dot[b] = cell_emb[cell_idx[b]] . W2 + b2
__global__ __launch_bounds__(64) void prep_kernel(const float* __restrict__ g_logits,
                                                  const float* __restrict__ alpha_logits,
                                                  const int* __restrict__ cell_idx,
                                                  const float* __restrict__ cell_emb,
                                                  const float* __restrict__ W2,
                                                  const float* __restrict__ b2,
                                                  float* __restrict__ gsign,
                                                  float* __restrict__ alph,
                                                  float* __restrict__ cell_dot) {
    int t = threadIdx.x;
    if (t < 6) gsign[t] = ((t & 1) ? -1.f : 1.f) * softplusf_(g_logits[t]);
    if (t < NSTEPS) alph[t] = sigmoidf_(alpha_logits[t]);
    int ci = cell_idx[t];
    float acc = b2[0];
    for (int hh = 0; hh < HID; ++hh) acc = fmaf(cell_emb[ci * HID + hh], W2[hh], acc);
    cell_dot[t] = acc;
}

// ---------------- CSR build (XCD-sliced by dst) ----------------

__global__ __launch_bounds__(256) void hist_kernel(const int* __restrict__ dst,
                                                   int* __restrict__ counts,
                                                   int total, int nblk) {
    int slice = blockIdx.x & (NSLICE - 1);
    int lo = slice * SLICE_SZ, hi = lo + SLICE_SZ;
    int stride = (nblk >> 3) * 256;
    for (int i = (blockIdx.x >> 3) * 256 + (int)threadIdx.x; i < total; i += stride) {
        int d = dst[i];
        if (d >= lo && d < hi) atomicAdd(&counts[d], 1);
    }
}

__global__ __launch_bounds__(256) void scan_kernel(const int* __restrict__ counts,
                                                   int* __restrict__ row_ptr,
                                                   int* __restrict__ cursor, int n) {
    __shared__ int sums[256];
    int tid = threadIdx.x;
    int seg = (n + 255) >> 8;
    int beg = tid * seg;
    int end = min(beg + seg, n);
    int s = 0;
    for (int i = beg; i < end; ++i) s += counts[i];
    sums[tid] = s;
    __syncthreads();
    if (tid == 0) {
        int run = 0;
        for (int i = 0; i < 256; ++i) { int v = sums[i]; sums[i] = run; run += v; }
        row_ptr[n] = run;
    }
    __syncthreads();
    int off = sums[tid];
    for (int i = beg; i < end; ++i) {
        row_ptr[i] = off;
        cursor[i]  = off;
        off += counts[i];
    }
}

__global__ __launch_bounds__(256) void scatter_kernel(const int* __restrict__ esrc,
                                                      const int* __restrict__ edst,
                                                      const float* __restrict__ eval,
                                                      const float* __restrict__ gsign,
                                                      int* __restrict__ cursor,
                                                      int2* __restrict__ entries,
                                                      int E, int total, int nblk) {
    int slice = blockIdx.x & (NSLICE - 1);
    int lo = slice * SLICE_SZ, hi = lo + SLICE_SZ;
    int stride = (nblk >> 3) * 256;
    for (int i = (blockIdx.x >> 3) * 256 + (int)threadIdx.x; i < total; i += stride) {
        int d = edst[i];
        if (d >= lo && d < hi) {
            // relation r = i / E via 5 compares (E not a power of two)
            int r = (i >= E) + (i >= 2 * E) + (i >= 3 * E) + (i >= 4 * E) + (i >= 5 * E);
            float coef = gsign[r] * eval[i];
            int pos = atomicAdd(&cursor[d], 1);
            entries[pos] = make_int2(esrc[i], __float_as_int(coef));
        }
    }
}

// ---------------- transpose (generic 64-tile) ----------------
// in[r*C + c] -> out[c*R + r]
__global__ __launch_bounds__(256) void transpose64(float* __restrict__ out,
                                                   const float* __restrict__ in,
                                                   int R, int C) {
    __shared__ float tile[64][65];
    int c0 = blockIdx.x * 64, r0 = blockIdx.y * 64;
    int tx = threadIdx.x & 63, ty = threadIdx.x >> 6;
#pragma unroll
    for (int i = 0; i < 16; ++i) {
        int r = r0 + ty + i * 4;
        int c = c0 + tx;
        tile[ty + i * 4][tx] = (r < R && c < C) ? in[(size_t)r * C + c] : 0.f;
    }
    __syncthreads();
#pragma unroll
    for (int i = 0; i < 16; ++i) {
        int c = c0 + ty + i * 4;
        int r = r0 + tx;
        if (c < C && r < R) out[(size_t)c * R + r] = tile[tx][ty + i * 4];
    }
}

// ---------------- propagation step ----------------
// One wave per node; lane = batch index. h layout: [N, 64].
// 16-entry batches: 8 uniform int4 loads -> 16 independent gathers -> 16 FMAs.
__global__ __launch_bounds__(256) void step_kernel(const float* __restrict__ h_in,
                                                   const float* __restrict__ h0,
                                                   float* __restrict__ h_out,
                                                   const int* __restrict__ row_ptr,
                                                   const int2* __restrict__ entries,
                                                   const float* __restrict__ alph,
                                                   int k) {
    int lane = threadIdx.x & 63;
    int node = blockIdx.x * 4 + (threadIdx.x >> 6);
    if (node >= N_NODES) return;
    int beg = __builtin_amdgcn_readfirstlane(row_ptr[node]);
    int end = __builtin_amdgcn_readfirstlane(row_ptr[node + 1]);
    float acc0 = 0.f, acc1 = 0.f, acc2 = 0.f, acc3 = 0.f;
    int e = beg;
    // peel to even e so int4 (16B) loads are aligned (entries is 256B-aligned)
    if ((e & 1) && e < end) {
        int2 a = entries[e];
        acc0 = fmaf(__int_as_float(a.y), h_in[a.x * 64 + lane], acc0);
        ++e;
    }
    for (; e + 16 <= end; e += 16) {
        int4 p[8];
#pragma unroll
        for (int j = 0; j < 8; ++j) p[j] = *(const int4*)(entries + e + 2 * j);
        float v[16];
#pragma unroll
        for (int j = 0; j < 8; ++j) {
            v[2 * j]     = h_in[p[j].x * 64 + lane];
            v[2 * j + 1] = h_in[p[j].z * 64 + lane];
        }
#pragma unroll
        for (int j = 0; j < 8; ++j) {
            acc0 = fmaf(__int_as_float(p[j].y), v[2 * j], acc0);
            acc1 = fmaf(__int_as_float(p[j].w), v[2 * j + 1], acc1);
        }
    }
    for (; e + 2 <= end; e += 2) {
        int4 p = *(const int4*)(entries + e);
        acc2 = fmaf(__int_as_float(p.y), h_in[p.x * 64 + lane], acc2);
        acc3 = fmaf(__int_as_float(p.w), h_in[p.z * 64 + lane], acc3);
    }
    if (e < end) {
        int2 a = entries[e];
        acc0 = fmaf(__int_as_float(a.y), h_in[a.x * 64 + lane], acc0);
    }
    float a = alph[k];
    int idx = node * 64 + lane;
    h_out[idx] = fmaf(a, h0[idx], (1.f - a) * ((acc0 + acc1) + (acc2 + acc3)));
}

// ---------------- decode ----------------

__global__ __launch_bounds__(256) void decode_kernel(float* __restrict__ y,
                                                     const float* __restrict__ ctl,
                                                     const float* __restrict__ u,
                                                     const float* __restrict__ h_bn,
                                                     const float* __restrict__ W1,
                                                     const float* __restrict__ b1,
                                                     const float* __restrict__ W2,
                                                     const float* __restrict__ cell_dot,
                                                     int total) {
    __shared__ float4 pack[HID];
    __shared__ float w2s[HID];
    if (threadIdx.x < HID) {
        int hh = threadIdx.x;
        pack[hh] = make_float4(W1[0 * HID + hh], W1[1 * HID + hh], W1[2 * HID + hh], b1[hh]);
        w2s[hh] = W2[hh];
    }
    __syncthreads();
    int idx = blockIdx.x * 256 + threadIdx.x;
    if (idx >= total) return;
    int b = idx / N_NODES;
    float xc = ctl[idx], xu = u[idx], xh = h_bn[idx];
    float acc = 0.f;
#pragma unroll 8
    for (int hh = 0; hh < HID; ++hh) {
        float4 p = pack[hh];
        float t = fmaf(xc, p.x, fmaf(xu, p.y, fmaf(xh, p.z, p.w)));
        t = fmaxf(t, 0.f);
        acc = fmaf(t, w2s[hh], acc);
    }
    y[idx] = acc + cell_dot[b];
}

// ---------------- launch ----------------

extern "C" void kernel_launch(void* const* d_in, const int* in_sizes, int n_in,
                              void* d_out, int out_size, void* d_ws, size_t ws_size,
                              hipStream_t stream) {
    const float* ctl          = (const float*)d_in[0];
    const float* u_raw        = (const float*)d_in[1];
    const int*   cell_idx     = (const int*)d_in[2];
    const int*   edge_src     = (const int*)d_in[3];
    const int*   edge_dst     = (const int*)d_in[4];
    const float* edge_val     = (const float*)d_in[5];
    const float* g_logits     = (const float*)d_in[6];
    const float* alpha_logits = (const float*)d_in[7];
    const float* cell_emb     = (const float*)d_in[8];
    const float* W1           = (const float*)d_in[9];
    const float* b1           = (const float*)d_in[10];
    const float* W2           = (const float*)d_in[11];
    const float* b2           = (const float*)d_in[12];
    float* y = (float*)d_out;

    const int TE = in_sizes[3];   // 6 * E
    const int E  = TE / 6;
    const int NB = N_NODES * 64;  // h elements

    char* ws = (char*)d_ws;
    size_t off = 0;
    auto alloc = [&](size_t bytes) -> char* {
        char* p = ws + off;
        off += (bytes + 255) & ~(size_t)255;
        return p;
    };
    int*   row_ptr  = (int*)alloc((N_NODES + 1) * sizeof(int));
    int*   counts   = (int*)alloc(N_NODES * sizeof(int));
    int*   cursor   = (int*)alloc(N_NODES * sizeof(int));
    int2*  entries  = (int2*)alloc((size_t)TE * sizeof(int2));
    float* u_t      = (float*)alloc((size_t)NB * sizeof(float));
    float* hA       = (float*)alloc((size_t)NB * sizeof(float));
    float* hB       = (float*)alloc((size_t)NB * sizeof(float));
    float* h_bn     = (float*)alloc((size_t)NB * sizeof(float));
    float* gsign    = (float*)alloc(8 * sizeof(float));
    float* alph     = (float*)alloc(8 * sizeof(float));
    float* cell_dot = (float*)alloc(64 * sizeof(float));

    // 0. tiny per-call constants
    prep_kernel<<<1, 64, 0, stream>>>(g_logits, alpha_logits, cell_idx, cell_emb,
                                      W2, b2, gsign, alph, cell_dot);

    // 1. Build combined dst-CSR with folded coefficients (XCD-sliced)
    hipMemsetAsync(counts, 0, N_NODES * sizeof(int), stream);
    const int NBLK = 2048;  // multiple of 8; blockIdx%8 -> XCD (round-robin dispatch)
    hist_kernel<<<NBLK, 256, 0, stream>>>(edge_dst, counts, TE, NBLK);
    scan_kernel<<<1, 256, 0, stream>>>(counts, row_ptr, cursor, N_NODES);
    scatter_kernel<<<NBLK, 256, 0, stream>>>(edge_src, edge_dst, edge_val,
                                             gsign, cursor, entries, E, TE, NBLK);

    // 2. u_raw [B,N] -> u_t [N,B]
    transpose64<<<dim3((N_NODES + 63) / 64, 1), 256, 0, stream>>>(u_t, u_raw, 64, N_NODES);

    // 3. 6 propagation steps, ping-pong
    const float* hin = u_t;
    float* hout = hA;
    for (int k = 0; k < NSTEPS; ++k) {
        hout = (k & 1) ? hB : hA;
        step_kernel<<<(N_NODES + 3) / 4, 256, 0, stream>>>(hin, u_t, hout, row_ptr,
                                                           entries, alph, k);
        hin = hout;
    }

    // 4. h_final [N,B] -> h_bn [B,N]
    transpose64<<<dim3(1, (N_NODES + 63) / 64), 256, 0, stream>>>(h_bn, hout, N_NODES, 64);

    // 5. decode
    decode_kernel<<<(out_size + 255) / 256, 256, 0, stream>>>(y, ctl, u_raw, h_bn,
                                                              W1, b1, W2, cell_dot, out_size);
}

// Round 3
// 582.644 us; speedup vs baseline: 1.5951x; 1.1209x over previous
//
#include <hip/hip_runtime.h>

#define N_NODES 20000
#define HID 64
#define NSTEPS 6
#define NSLICE 8
#define SLICE_SZ (N_NODES / NSLICE)  // 2500
#define SUBB 64                      // sub-chunks per slice
#define NBLK (NSLICE * SUBB)         // 512 blocks for hist2d/scatter2

__device__ __forceinline__ float softplusf_(float x) {
    return (x > 0.f) ? (x + log1pf(expf(-x))) : log1pf(expf(x));
}
__device__ __forceinline__ float sigmoidf_(float x) {
    return 1.f / (1.f + expf(-x));
}

// ---------------- prep: tiny per-call constants ----------------
__global__ __launch_bounds__(64) void prep_kernel(const float* __restrict__ g_logits,
                                                  const float* __restrict__ alpha_logits,
                                                  const int* __restrict__ cell_idx,
                                                  const float* __restrict__ cell_emb,
                                                  const float* __restrict__ W2,
                                                  const float* __restrict__ b2,
                                                  float* __restrict__ gsign,
                                                  float* __restrict__ alph,
                                                  float* __restrict__ cell_dot) {
    int t = threadIdx.x;
    if (t < 6) gsign[t] = ((t & 1) ? -1.f : 1.f) * softplusf_(g_logits[t]);
    if (t < NSTEPS) alph[t] = sigmoidf_(alpha_logits[t]);
    int ci = cell_idx[t];
    float acc = b2[0];
    for (int hh = 0; hh < HID; ++hh) acc = fmaf(cell_emb[ci * HID + hh], W2[hh], acc);
    cell_dot[t] = acc;
}

// ---------------- CSR build: atomic-free privatized counting sort ----------------
// Block bk: slice = bk & 7 (dst range), sub = bk >> 3 (edge chunk).
// Pass A: LDS histogram -> blkcnt[slice][sub][bin]  (plain stores, no global atomics)

__global__ __launch_bounds__(256) void hist2d_kernel(const int* __restrict__ edst,
                                                     int* __restrict__ blkcnt, int TE) {
    __shared__ int lh[SLICE_SZ];
    int bk = blockIdx.x;
    int slice = bk & (NSLICE - 1);
    int sub = bk >> 3;
    for (int b = threadIdx.x; b < SLICE_SZ; b += 256) lh[b] = 0;
    __syncthreads();
    int chunk = ((TE + SUBB - 1) / SUBB + 255) & ~255;
    int lo_e = sub * chunk;
    int hi_e = min(lo_e + chunk, TE);
    int lo = slice * SLICE_SZ;
    for (int i = lo_e + (int)threadIdx.x; i < hi_e; i += 256) {
        unsigned d = (unsigned)(edst[i] - lo);
        if (d < SLICE_SZ) atomicAdd(&lh[d], 1);  // LDS atomic
    }
    __syncthreads();
    int* out = blkcnt + (size_t)(slice * SUBB + sub) * SLICE_SZ;
    for (int b = threadIdx.x; b < SLICE_SZ; b += 256) out[b] = lh[b];
}

// Pass B: per-bin exclusive prefix across the 64 sub-blocks; emit total counts.
__global__ __launch_bounds__(256) void colscan_kernel(int* __restrict__ blkcnt,
                                                      int* __restrict__ counts) {
    int n = blockIdx.x * 256 + threadIdx.x;
    if (n >= N_NODES) return;
    int slice = n / SLICE_SZ, bin = n % SLICE_SZ;
    size_t base = (size_t)slice * SUBB * SLICE_SZ + bin;
    int run = 0;
#pragma unroll 8
    for (int s = 0; s < SUBB; ++s) {
        size_t idx = base + (size_t)s * SLICE_SZ;
        int t = blkcnt[idx];
        blkcnt[idx] = run;
        run += t;
    }
    counts[n] = run;
}

// Pass C: row_ptr from counts.
__global__ __launch_bounds__(256) void scan_kernel(const int* __restrict__ counts,
                                                   int* __restrict__ row_ptr, int n) {
    __shared__ int sums[256];
    int tid = threadIdx.x;
    int seg = (n + 255) >> 8;
    int beg = tid * seg;
    int end = min(beg + seg, n);
    int s = 0;
    for (int i = beg; i < end; ++i) s += counts[i];
    sums[tid] = s;
    __syncthreads();
    if (tid == 0) {
        int run = 0;
        for (int i = 0; i < 256; ++i) { int v = sums[i]; sums[i] = run; run += v; }
        row_ptr[n] = run;
    }
    __syncthreads();
    int off = sums[tid];
    for (int i = beg; i < end; ++i) {
        row_ptr[i] = off;
        off += counts[i];
    }
}

// Pass D: placement with LDS ranks only; entry writes stay slice-local (XCD-local).
__global__ __launch_bounds__(256) void scatter2_kernel(const int* __restrict__ esrc,
                                                       const int* __restrict__ edst,
                                                       const float* __restrict__ eval,
                                                       const float* __restrict__ gsign,
                                                       const int* __restrict__ row_ptr,
                                                       const int* __restrict__ blkcnt,
                                                       int2* __restrict__ entries,
                                                       int E, int TE) {
    __shared__ int lbase[SLICE_SZ];  // row_ptr[node] + per-block offset, then rank cursor
    int bk = blockIdx.x;
    int slice = bk & (NSLICE - 1);
    int sub = bk >> 3;
    int lo = slice * SLICE_SZ;
    const int* boff = blkcnt + (size_t)(slice * SUBB + sub) * SLICE_SZ;
    for (int b = threadIdx.x; b < SLICE_SZ; b += 256) lbase[b] = row_ptr[lo + b] + boff[b];
    __syncthreads();
    int chunk = ((TE + SUBB - 1) / SUBB + 255) & ~255;
    int lo_e = sub * chunk;
    int hi_e = min(lo_e + chunk, TE);
    for (int i = lo_e + (int)threadIdx.x; i < hi_e; i += 256) {
        unsigned d = (unsigned)(edst[i] - lo);
        if (d < SLICE_SZ) {
            int r = (i >= E) + (i >= 2 * E) + (i >= 3 * E) + (i >= 4 * E) + (i >= 5 * E);
            float coef = gsign[r] * eval[i];
            int pos = atomicAdd(&lbase[d], 1);  // LDS atomic; base+rank combined
            entries[pos] = make_int2(esrc[i], __float_as_int(coef));
        }
    }
}

// ---------------- transpose (generic 64-tile) ----------------
__global__ __launch_bounds__(256) void transpose64(float* __restrict__ out,
                                                   const float* __restrict__ in,
                                                   int R, int C) {
    __shared__ float tile[64][65];
    int c0 = blockIdx.x * 64, r0 = blockIdx.y * 64;
    int tx = threadIdx.x & 63, ty = threadIdx.x >> 6;
#pragma unroll
    for (int i = 0; i < 16; ++i) {
        int r = r0 + ty + i * 4;
        int c = c0 + tx;
        tile[ty + i * 4][tx] = (r < R && c < C) ? in[(size_t)r * C + c] : 0.f;
    }
    __syncthreads();
#pragma unroll
    for (int i = 0; i < 16; ++i) {
        int c = c0 + ty + i * 4;
        int r = r0 + tx;
        if (c < C && r < R) out[(size_t)c * R + r] = tile[tx][ty + i * 4];
    }
}

// ---------------- propagation step ----------------
__global__ __launch_bounds__(256) void step_kernel(const float* __restrict__ h_in,
                                                   const float* __restrict__ h0,
                                                   float* __restrict__ h_out,
                                                   const int* __restrict__ row_ptr,
                                                   const int2* __restrict__ entries,
                                                   const float* __restrict__ alph,
                                                   int k) {
    int lane = threadIdx.x & 63;
    int node = blockIdx.x * 4 + (threadIdx.x >> 6);
    if (node >= N_NODES) return;
    int beg = __builtin_amdgcn_readfirstlane(row_ptr[node]);
    int end = __builtin_amdgcn_readfirstlane(row_ptr[node + 1]);
    float acc0 = 0.f, acc1 = 0.f, acc2 = 0.f, acc3 = 0.f;
    int e = beg;
    if ((e & 1) && e < end) {
        int2 a = entries[e];
        acc0 = fmaf(__int_as_float(a.y), h_in[a.x * 64 + lane], acc0);
        ++e;
    }
    for (; e + 16 <= end; e += 16) {
        int4 p[8];
#pragma unroll
        for (int j = 0; j < 8; ++j) p[j] = *(const int4*)(entries + e + 2 * j);
        float v[16];
#pragma unroll
        for (int j = 0; j < 8; ++j) {
            v[2 * j]     = h_in[p[j].x * 64 + lane];
            v[2 * j + 1] = h_in[p[j].z * 64 + lane];
        }
#pragma unroll
        for (int j = 0; j < 8; ++j) {
            acc0 = fmaf(__int_as_float(p[j].y), v[2 * j], acc0);
            acc1 = fmaf(__int_as_float(p[j].w), v[2 * j + 1], acc1);
        }
    }
    for (; e + 2 <= end; e += 2) {
        int4 p = *(const int4*)(entries + e);
        acc2 = fmaf(__int_as_float(p.y), h_in[p.x * 64 + lane], acc2);
        acc3 = fmaf(__int_as_float(p.w), h_in[p.z * 64 + lane], acc3);
    }
    if (e < end) {
        int2 a = entries[e];
        acc0 = fmaf(__int_as_float(a.y), h_in[a.x * 64 + lane], acc0);
    }
    float a = alph[k];
    int idx = node * 64 + lane;
    h_out[idx] = fmaf(a, h0[idx], (1.f - a) * ((acc0 + acc1) + (acc2 + acc3)));
}

// ---------------- decode ----------------
__global__ __launch_bounds__(256) void decode_kernel(float* __restrict__ y,
                                                     const float* __restrict__ ctl,
                                                     const float* __restrict__ u,
                                                     const float* __restrict__ h_bn,
                                                     const float* __restrict__ W1,
                                                     const float* __restrict__ b1,
                                                     const float* __restrict__ W2,
                                                     const float* __restrict__ cell_dot,
                                                     int total) {
    __shared__ float4 pack[HID];
    __shared__ float w2s[HID];
    if (threadIdx.x < HID) {
        int hh = threadIdx.x;
        pack[hh] = make_float4(W1[0 * HID + hh], W1[1 * HID + hh], W1[2 * HID + hh], b1[hh]);
        w2s[hh] = W2[hh];
    }
    __syncthreads();
    int idx = blockIdx.x * 256 + threadIdx.x;
    if (idx >= total) return;
    int b = idx / N_NODES;
    float xc = ctl[idx], xu = u[idx], xh = h_bn[idx];
    float acc = 0.f;
#pragma unroll 8
    for (int hh = 0; hh < HID; ++hh) {
        float4 p = pack[hh];
        float t = fmaf(xc, p.x, fmaf(xu, p.y, fmaf(xh, p.z, p.w)));
        t = fmaxf(t, 0.f);
        acc = fmaf(t, w2s[hh], acc);
    }
    y[idx] = acc + cell_dot[b];
}

// ---------------- launch ----------------
extern "C" void kernel_launch(void* const* d_in, const int* in_sizes, int n_in,
                              void* d_out, int out_size, void* d_ws, size_t ws_size,
                              hipStream_t stream) {
    const float* ctl          = (const float*)d_in[0];
    const float* u_raw        = (const float*)d_in[1];
    const int*   cell_idx     = (const int*)d_in[2];
    const int*   edge_src     = (const int*)d_in[3];
    const int*   edge_dst     = (const int*)d_in[4];
    const float* edge_val     = (const float*)d_in[5];
    const float* g_logits     = (const float*)d_in[6];
    const float* alpha_logits = (const float*)d_in[7];
    const float* cell_emb     = (const float*)d_in[8];
    const float* W1           = (const float*)d_in[9];
    const float* b1           = (const float*)d_in[10];
    const float* W2           = (const float*)d_in[11];
    const float* b2           = (const float*)d_in[12];
    float* y = (float*)d_out;

    const int TE = in_sizes[3];   // 6 * E
    const int E  = TE / 6;
    const int NB = N_NODES * 64;  // h elements

    char* ws = (char*)d_ws;
    size_t off = 0;
    auto alloc = [&](size_t bytes) -> char* {
        char* p = ws + off;
        off += (bytes + 255) & ~(size_t)255;
        return p;
    };
    int*   row_ptr  = (int*)alloc((N_NODES + 1) * sizeof(int));
    int*   counts   = (int*)alloc(N_NODES * sizeof(int));
    int*   blkcnt   = (int*)alloc((size_t)NSLICE * SUBB * SLICE_SZ * sizeof(int));
    int2*  entries  = (int2*)alloc((size_t)TE * sizeof(int2));
    float* u_t      = (float*)alloc((size_t)NB * sizeof(float));
    float* hA       = (float*)alloc((size_t)NB * sizeof(float));
    float* hB       = (float*)alloc((size_t)NB * sizeof(float));
    float* h_bn     = (float*)alloc((size_t)NB * sizeof(float));
    float* gsign    = (float*)alloc(8 * sizeof(float));
    float* alph     = (float*)alloc(8 * sizeof(float));
    float* cell_dot = (float*)alloc(64 * sizeof(float));

    // 0. tiny per-call constants
    prep_kernel<<<1, 64, 0, stream>>>(g_logits, alpha_logits, cell_idx, cell_emb,
                                      W2, b2, gsign, alph, cell_dot);

    // 1. CSR build — zero global atomics
    hist2d_kernel<<<NBLK, 256, 0, stream>>>(edge_dst, blkcnt, TE);
    colscan_kernel<<<(N_NODES + 255) / 256, 256, 0, stream>>>(blkcnt, counts);
    scan_kernel<<<1, 256, 0, stream>>>(counts, row_ptr, N_NODES);
    scatter2_kernel<<<NBLK, 256, 0, stream>>>(edge_src, edge_dst, edge_val, gsign,
                                              row_ptr, blkcnt, entries, E, TE);

    // 2. u_raw [B,N] -> u_t [N,B]
    transpose64<<<dim3((N_NODES + 63) / 64, 1), 256, 0, stream>>>(u_t, u_raw, 64, N_NODES);

    // 3. 6 propagation steps, ping-pong
    const float* hin = u_t;
    float* hout = hA;
    for (int k = 0; k < NSTEPS; ++k) {
        hout = (k & 1) ? hB : hA;
        step_kernel<<<(N_NODES + 3) / 4, 256, 0, stream>>>(hin, u_t, hout, row_ptr,
                                                           entries, alph, k);
        hin = hout;
    }

    // 4. h_final [N,B] -> h_bn [B,N]
    transpose64<<<dim3(1, (N_NODES + 63) / 64), 256, 0, stream>>>(h_bn, hout, N_NODES, 64);

    // 5. decode
    decode_kernel<<<(out_size + 255) / 256, 256, 0, stream>>>(y, ctl, u_raw, h_bn,
                                                              W1, b1, W2, cell_dot, out_size);
}

// Round 4
// 452.282 us; speedup vs baseline: 2.0549x; 1.2882x over previous
//
#include <hip/hip_runtime.h>

#define N_NODES 20000
#define HID 64
#define NSTEPS 6
#define NSLICE 8
#define SLICE_SZ (N_NODES / NSLICE)  // 2500
#define SUBB 64                      // sub-chunks per slice (phase 2)
#define NBLK (NSLICE * SUBB)         // 512 blocks for hist/scatter
#define NB1 512                      // blocks for count/bucket phase
#define MAGIC 13422                  // floor(d*13422 / 2^25) == d/2500 for d < 20000

__device__ __forceinline__ int slice_of(int d) {
    return (int)(((unsigned)d * (unsigned)MAGIC) >> 25);
}
__device__ __forceinline__ unsigned short f2bf(float x) {  // RNE f32->bf16
    unsigned u = __float_as_uint(x);
    return (unsigned short)((u + 0x7FFFu + ((u >> 16) & 1u)) >> 16);
}
__device__ __forceinline__ float bf2f(unsigned short b) {
    return __uint_as_float((unsigned)b << 16);
}
__device__ __forceinline__ float softplusf_(float x) {
    return (x > 0.f) ? (x + log1pf(expf(-x))) : log1pf(expf(x));
}
__device__ __forceinline__ float sigmoidf_(float x) {
    return 1.f / (1.f + expf(-x));
}

// ---------------- prep: tiny per-call constants ----------------
__global__ __launch_bounds__(64) void prep_kernel(const float* __restrict__ g_logits,
                                                  const float* __restrict__ alpha_logits,
                                                  const int* __restrict__ cell_idx,
                                                  const float* __restrict__ cell_emb,
                                                  const float* __restrict__ W2,
                                                  const float* __restrict__ b2,
                                                  float* __restrict__ gsign,
                                                  float* __restrict__ alph,
                                                  float* __restrict__ cell_dot) {
    int t = threadIdx.x;
    if (t < 6) gsign[t] = ((t & 1) ? -1.f : 1.f) * softplusf_(g_logits[t]);
    if (t < NSTEPS) alph[t] = sigmoidf_(alpha_logits[t]);
    int ci = cell_idx[t];
    float acc = b2[0];
    for (int hh = 0; hh < HID; ++hh) acc = fmaf(cell_emb[ci * HID + hh], W2[hh], acc);
    cell_dot[t] = acc;
}

// ---------------- P0: per-(block,slice) edge counts (read edges ONCE) ----------------
__global__ __launch_bounds__(256) void count8_kernel(const int* __restrict__ edst,
                                                     int* __restrict__ gcnt, int TE) {
    __shared__ int lh[8];
    int bk = blockIdx.x;
    int lane = threadIdx.x & 63;
    if (threadIdx.x < 8) lh[threadIdx.x] = 0;
    __syncthreads();
    int chunk = ((TE + NB1 - 1) / NB1 + 255) & ~255;
    int lo = bk * chunk;
    int hi = min(lo + chunk, TE);
    int my = 0;  // lane q (<8) accumulates slice-q count for its wave
    for (int ii = 0; ii < chunk; ii += 256) {
        int i = lo + ii + (int)threadIdx.x;
        bool act = i < hi;
        int s = -1;
        if (act) s = slice_of(__builtin_nontemporal_load(edst + i));
#pragma unroll
        for (int q = 0; q < 8; ++q) {
            unsigned long long b = __ballot(s == q);
            if (lane == q) my += (int)__popcll(b);
        }
    }
    if (lane < 8) atomicAdd(&lh[lane], my);
    __syncthreads();
    if (threadIdx.x < 8) gcnt[bk * 8 + threadIdx.x] = lh[threadIdx.x];
}

// ---------------- P0b: scan gcnt -> blkoff (excl. per column) + bbase[9] ----------------
__global__ __launch_bounds__(256) void scan8_kernel(const int* __restrict__ gcnt,
                                                    int* __restrict__ blkoff,
                                                    int* __restrict__ bbase) {
    __shared__ int psum[8][33];
    int tid = threadIdx.x;
    int s = tid >> 5, g = tid & 31;
    const int per = NB1 / 32;  // 16
    int sum = 0;
    for (int b = g * per; b < (g + 1) * per; ++b) sum += gcnt[b * 8 + s];
    psum[s][g] = sum;
    __syncthreads();
    if (tid < 8) {
        int run = 0;
        for (int i = 0; i < 32; ++i) { int v = psum[tid][i]; psum[tid][i] = run; run += v; }
        psum[tid][32] = run;
    }
    __syncthreads();
    int run = psum[s][g];
    for (int b = g * per; b < (g + 1) * per; ++b) {
        blkoff[b * 8 + s] = run;
        run += gcnt[b * 8 + s];
    }
    if (tid == 0) {
        int acc = 0;
        bbase[0] = 0;
        for (int q = 0; q < 8; ++q) { acc += psum[q][32]; bbase[q + 1] = acc; }
    }
}

// ---------------- P1: bucket edges by slice; pack {src | dl<<16, coef} ----------------
__global__ __launch_bounds__(256) void bucket_kernel(const int* __restrict__ esrc,
                                                     const int* __restrict__ edst,
                                                     const float* __restrict__ eval,
                                                     const float* __restrict__ gsign,
                                                     const int* __restrict__ blkoff,
                                                     const int* __restrict__ bbase,
                                                     int2* __restrict__ bucket,
                                                     int E, int TE) {
    __shared__ int lcur[8];
    int bk = blockIdx.x;
    int lane = threadIdx.x & 63;
    if (threadIdx.x < 8) lcur[threadIdx.x] = bbase[threadIdx.x] + blkoff[bk * 8 + threadIdx.x];
    __syncthreads();
    int chunk = ((TE + NB1 - 1) / NB1 + 255) & ~255;
    int lo = bk * chunk;
    int hi = min(lo + chunk, TE);
    for (int ii = 0; ii < chunk; ii += 256) {
        int i = lo + ii + (int)threadIdx.x;
        bool act = i < hi;
        int s = -1, meta = 0, cb = 0;
        if (act) {
            int d  = __builtin_nontemporal_load(edst + i);
            int sv = __builtin_nontemporal_load(esrc + i);
            float ev = __builtin_nontemporal_load(eval + i);
            s = slice_of(d);
            int dl = d - s * SLICE_SZ;
            meta = sv | (dl << 16);
            int r = (i >= E) + (i >= 2 * E) + (i >= 3 * E) + (i >= 4 * E) + (i >= 5 * E);
            cb = __float_as_int(gsign[r] * ev);
        }
        int pos = 0;
#pragma unroll
        for (int q = 0; q < 8; ++q) {
            unsigned long long b = __ballot(s == q);
            if (b) {
                int leader = (int)__ffsll(b) - 1;
                int base = 0;
                if (lane == leader) base = atomicAdd(&lcur[q], (int)__popcll(b));
                base = __shfl(base, leader);
                if (s == q) pos = base + (int)__popcll(b & ((1ull << lane) - 1ull));
            }
        }
        if (act) bucket[pos] = make_int2(meta, cb);
    }
}

// ---------------- P2: per-(slice,sub) LDS histogram from the bucket ----------------
__global__ __launch_bounds__(256) void hist2db_kernel(const int2* __restrict__ bucket,
                                                      const int* __restrict__ bbase,
                                                      int* __restrict__ blkcnt) {
    __shared__ int lh[SLICE_SZ];
    int bk = blockIdx.x;
    int slice = bk & (NSLICE - 1);
    int sub = bk >> 3;
    for (int b = threadIdx.x; b < SLICE_SZ; b += 256) lh[b] = 0;
    __syncthreads();
    int lo = bbase[slice];
    int total = bbase[slice + 1] - lo;
    int chunk = ((total + SUBB - 1) / SUBB + 255) & ~255;
    int beg = lo + sub * chunk;
    int end = min(beg + chunk, lo + total);
    const int* mp = (const int*)bucket;
    for (int i = beg + (int)threadIdx.x; i < end; i += 256) {
        int meta = __builtin_nontemporal_load(mp + 2 * (size_t)i);
        atomicAdd(&lh[((unsigned)meta) >> 16], 1);
    }
    __syncthreads();
    int* out = blkcnt + (size_t)(slice * SUBB + sub) * SLICE_SZ;
    for (int b = threadIdx.x; b < SLICE_SZ; b += 256) out[b] = lh[b];
}

// ---------------- P3a: per-bin exclusive prefix across sub-blocks ----------------
__global__ __launch_bounds__(256) void colscan_kernel(int* __restrict__ blkcnt,
                                                      int* __restrict__ counts) {
    int n = blockIdx.x * 256 + threadIdx.x;
    if (n >= N_NODES) return;
    int slice = n / SLICE_SZ, bin = n % SLICE_SZ;
    size_t base = (size_t)slice * SUBB * SLICE_SZ + bin;
    int run = 0;
#pragma unroll 8
    for (int s = 0; s < SUBB; ++s) {
        size_t idx = base + (size_t)s * SLICE_SZ;
        int t = blkcnt[idx];
        blkcnt[idx] = run;
        run += t;
    }
    counts[n] = run;
}

// ---------------- P3b: row_ptr from counts ----------------
__global__ __launch_bounds__(256) void scan_kernel(const int* __restrict__ counts,
                                                   int* __restrict__ row_ptr, int n) {
    __shared__ int sums[256];
    int tid = threadIdx.x;
    int seg = (n + 255) >> 8;
    int beg = tid * seg;
    int end = min(beg + seg, n);
    int s = 0;
    for (int i = beg; i < end; ++i) s += counts[i];
    sums[tid] = s;
    __syncthreads();
    if (tid == 0) {
        int run = 0;
        for (int i = 0; i < 256; ++i) { int v = sums[i]; sums[i] = run; run += v; }
        row_ptr[n] = run;
    }
    __syncthreads();
    int off = sums[tid];
    for (int i = beg; i < end; ++i) {
        row_ptr[i] = off;
        off += counts[i];
    }
}

// ---------------- P4: placement from slice-local bucket (XCD-local writes) ----------------
__global__ __launch_bounds__(256) void scatter2b_kernel(const int2* __restrict__ bucket,
                                                        const int* __restrict__ bbase,
                                                        const int* __restrict__ row_ptr,
                                                        const int* __restrict__ blkcnt,
                                                        int2* __restrict__ entries) {
    __shared__ int lbase[SLICE_SZ];
    int bk = blockIdx.x;
    int slice = bk & (NSLICE - 1);
    int sub = bk >> 3;
    int lo_n = slice * SLICE_SZ;
    const int* boff = blkcnt + (size_t)(slice * SUBB + sub) * SLICE_SZ;
    for (int b = threadIdx.x; b < SLICE_SZ; b += 256) lbase[b] = row_ptr[lo_n + b] + boff[b];
    __syncthreads();
    int lo = bbase[slice];
    int total = bbase[slice + 1] - lo;
    int chunk = ((total + SUBB - 1) / SUBB + 255) & ~255;
    int beg = lo + sub * chunk;
    int end = min(beg + chunk, lo + total);
    for (int i = beg + (int)threadIdx.x; i < end; i += 256) {
        long long rec = __builtin_nontemporal_load((const long long*)bucket + i);
        int meta = (int)rec;
        int cb = (int)(rec >> 32);
        int pos = atomicAdd(&lbase[((unsigned)meta) >> 16], 1);
        entries[pos] = make_int2(meta & 0xFFFF, cb);
    }
}

// ---------------- transpose (64-tile), optional bf16 side output ----------------
// in[r*C + c] -> out[c*R + r] (and outb if non-null)
__global__ __launch_bounds__(256) void transpose64(float* __restrict__ out,
                                                   unsigned short* __restrict__ outb,
                                                   const float* __restrict__ in,
                                                   int R, int C) {
    __shared__ float tile[64][65];
    int c0 = blockIdx.x * 64, r0 = blockIdx.y * 64;
    int tx = threadIdx.x & 63, ty = threadIdx.x >> 6;
#pragma unroll
    for (int i = 0; i < 16; ++i) {
        int r = r0 + ty + i * 4;
        int c = c0 + tx;
        tile[ty + i * 4][tx] = (r < R && c < C) ? in[(size_t)r * C + c] : 0.f;
    }
    __syncthreads();
#pragma unroll
    for (int i = 0; i < 16; ++i) {
        int c = c0 + ty + i * 4;
        int r = r0 + tx;
        if (c < C && r < R) {
            float v = tile[tx][ty + i * 4];
            out[(size_t)c * R + r] = v;
            if (outb) outb[(size_t)c * R + r] = f2bf(v);
        }
    }
}

// ---------------- propagation step (bf16 gathers, fp32 accumulate) ----------------
__global__ __launch_bounds__(256) void step_kernel(const unsigned short* __restrict__ h_in,
                                                   const float* __restrict__ h0,
                                                   unsigned short* __restrict__ h_out,
                                                   float* __restrict__ hF,
                                                   const int* __restrict__ row_ptr,
                                                   const int2* __restrict__ entries,
                                                   const float* __restrict__ alph,
                                                   int k) {
    int lane = threadIdx.x & 63;
    int node = blockIdx.x * 4 + (threadIdx.x >> 6);
    if (node >= N_NODES) return;
    int beg = __builtin_amdgcn_readfirstlane(row_ptr[node]);
    int end = __builtin_amdgcn_readfirstlane(row_ptr[node + 1]);
    float acc0 = 0.f, acc1 = 0.f, acc2 = 0.f, acc3 = 0.f;
    int e = beg;
    if ((e & 1) && e < end) {
        int2 a = entries[e];
        acc0 = fmaf(__int_as_float(a.y), bf2f(h_in[a.x * 64 + lane]), acc0);
        ++e;
    }
    for (; e + 16 <= end; e += 16) {
        int4 p[8];
#pragma unroll
        for (int j = 0; j < 8; ++j) p[j] = *(const int4*)(entries + e + 2 * j);
        float v[16];
#pragma unroll
        for (int j = 0; j < 8; ++j) {
            v[2 * j]     = bf2f(h_in[p[j].x * 64 + lane]);
            v[2 * j + 1] = bf2f(h_in[p[j].z * 64 + lane]);
        }
#pragma unroll
        for (int j = 0; j < 8; ++j) {
            acc0 = fmaf(__int_as_float(p[j].y), v[2 * j], acc0);
            acc1 = fmaf(__int_as_float(p[j].w), v[2 * j + 1], acc1);
        }
    }
    for (; e + 2 <= end; e += 2) {
        int4 p = *(const int4*)(entries + e);
        acc2 = fmaf(__int_as_float(p.y), bf2f(h_in[p.x * 64 + lane]), acc2);
        acc3 = fmaf(__int_as_float(p.w), bf2f(h_in[p.z * 64 + lane]), acc3);
    }
    if (e < end) {
        int2 a = entries[e];
        acc0 = fmaf(__int_as_float(a.y), bf2f(h_in[a.x * 64 + lane]), acc0);
    }
    float a = alph[k];
    int idx = node * 64 + lane;
    float r = fmaf(a, h0[idx], (1.f - a) * ((acc0 + acc1) + (acc2 + acc3)));
    h_out[idx] = f2bf(r);
    hF[idx] = r;  // stream-serialized: after step 5 this holds the final fp32 h
}

// ---------------- decode ----------------
__global__ __launch_bounds__(256) void decode_kernel(float* __restrict__ y,
                                                     const float* __restrict__ ctl,
                                                     const float* __restrict__ u,
                                                     const float* __restrict__ h_bn,
                                                     const float* __restrict__ W1,
                                                     const float* __restrict__ b1,
                                                     const float* __restrict__ W2,
                                                     const float* __restrict__ cell_dot,
                                                     int total) {
    __shared__ float4 pack[HID];
    __shared__ float w2s[HID];
    if (threadIdx.x < HID) {
        int hh = threadIdx.x;
        pack[hh] = make_float4(W1[0 * HID + hh], W1[1 * HID + hh], W1[2 * HID + hh], b1[hh]);
        w2s[hh] = W2[hh];
    }
    __syncthreads();
    int idx = blockIdx.x * 256 + threadIdx.x;
    if (idx >= total) return;
    int b = idx / N_NODES;
    float xc = ctl[idx], xu = u[idx], xh = h_bn[idx];
    float acc = 0.f;
#pragma unroll 8
    for (int hh = 0; hh < HID; ++hh) {
        float4 p = pack[hh];
        float t = fmaf(xc, p.x, fmaf(xu, p.y, fmaf(xh, p.z, p.w)));
        t = fmaxf(t, 0.f);
        acc = fmaf(t, w2s[hh], acc);
    }
    y[idx] = acc + cell_dot[b];
}

// ---------------- launch ----------------
extern "C" void kernel_launch(void* const* d_in, const int* in_sizes, int n_in,
                              void* d_out, int out_size, void* d_ws, size_t ws_size,
                              hipStream_t stream) {
    const float* ctl          = (const float*)d_in[0];
    const float* u_raw        = (const float*)d_in[1];
    const int*   cell_idx     = (const int*)d_in[2];
    const int*   edge_src     = (const int*)d_in[3];
    const int*   edge_dst     = (const int*)d_in[4];
    const float* edge_val     = (const float*)d_in[5];
    const float* g_logits     = (const float*)d_in[6];
    const float* alpha_logits = (const float*)d_in[7];
    const float* cell_emb     = (const float*)d_in[8];
    const float* W1           = (const float*)d_in[9];
    const float* b1           = (const float*)d_in[10];
    const float* W2           = (const float*)d_in[11];
    const float* b2           = (const float*)d_in[12];
    float* y = (float*)d_out;

    const int TE = in_sizes[3];   // 6 * E
    const int E  = TE / 6;
    const int NB = N_NODES * 64;  // h elements

    char* ws = (char*)d_ws;
    size_t off = 0;
    auto alloc = [&](size_t bytes) -> char* {
        char* p = ws + off;
        off += (bytes + 255) & ~(size_t)255;
        return p;
    };
    int*  row_ptr = (int*)alloc((N_NODES + 1) * sizeof(int));
    int*  counts  = (int*)alloc(N_NODES * sizeof(int));
    int*  blkcnt  = (int*)alloc((size_t)NSLICE * SUBB * SLICE_SZ * sizeof(int));
    int*  gcnt    = (int*)alloc((size_t)NB1 * 8 * sizeof(int));
    int*  blkoff  = (int*)alloc((size_t)NB1 * 8 * sizeof(int));
    int*  bbase   = (int*)alloc(16 * sizeof(int));
    int2* entries = (int2*)alloc((size_t)TE * sizeof(int2));
    // overlay: bucket (build phase) then h buffers (propagate phase) — stream-serialized
    size_t need_h = (size_t)NB * (2 + 2 + 2 + 4 + 4);
    size_t ov_sz = (size_t)TE * sizeof(int2);
    if (ov_sz < need_h) ov_sz = need_h;
    char* overlay = alloc(ov_sz);
    float* u_t      = (float*)alloc((size_t)NB * sizeof(float));
    float* gsign    = (float*)alloc(8 * sizeof(float));
    float* alph     = (float*)alloc(8 * sizeof(float));
    float* cell_dot = (float*)alloc(64 * sizeof(float));

    int2* bucket = (int2*)overlay;
    unsigned short* ubf = (unsigned short*)overlay;                       // NB*2
    unsigned short* bfA = (unsigned short*)(overlay + (size_t)NB * 2);    // NB*2
    unsigned short* bfB = (unsigned short*)(overlay + (size_t)NB * 4);    // NB*2
    float* hF   = (float*)(overlay + (size_t)NB * 6);                     // NB*4
    float* h_bn = (float*)(overlay + (size_t)NB * 10);                    // NB*4

    // 0. tiny per-call constants
    prep_kernel<<<1, 64, 0, stream>>>(g_logits, alpha_logits, cell_idx, cell_emb,
                                      W2, b2, gsign, alph, cell_dot);

    // 1. CSR build — edges read once, zero global atomics, XCD-local placement
    count8_kernel<<<NB1, 256, 0, stream>>>(edge_dst, gcnt, TE);
    scan8_kernel<<<1, 256, 0, stream>>>(gcnt, blkoff, bbase);
    bucket_kernel<<<NB1, 256, 0, stream>>>(edge_src, edge_dst, edge_val, gsign,
                                           blkoff, bbase, bucket, E, TE);
    hist2db_kernel<<<NBLK, 256, 0, stream>>>(bucket, bbase, blkcnt);
    colscan_kernel<<<(N_NODES + 255) / 256, 256, 0, stream>>>(blkcnt, counts);
    scan_kernel<<<1, 256, 0, stream>>>(counts, row_ptr, N_NODES);
    scatter2b_kernel<<<NBLK, 256, 0, stream>>>(bucket, bbase, row_ptr, blkcnt, entries);

    // 2. u_raw [B,N] -> u_t [N,B] (fp32) + ubf (bf16)   [bucket is dead now]
    transpose64<<<dim3((N_NODES + 63) / 64, 1), 256, 0, stream>>>(u_t, ubf, u_raw,
                                                                  64, N_NODES);

    // 3. 6 propagation steps: bf16 ping-pong, fp32 shadow in hF
    const unsigned short* hin = ubf;
    for (int k = 0; k < NSTEPS; ++k) {
        unsigned short* hout = (k & 1) ? bfB : bfA;
        step_kernel<<<(N_NODES + 3) / 4, 256, 0, stream>>>(hin, u_t, hout, hF,
                                                           row_ptr, entries, alph, k);
        hin = hout;
    }

    // 4. hF [N,64] -> h_bn [B,N]
    transpose64<<<dim3(1, (N_NODES + 63) / 64), 256, 0, stream>>>(h_bn, (unsigned short*)0,
                                                                  hF, N_NODES, 64);

    // 5. decode
    decode_kernel<<<(out_size + 255) / 256, 256, 0, stream>>>(y, ctl, u_raw, h_bn,
                                                              W1, b1, W2, cell_dot, out_size);
}

// Round 5
// 440.533 us; speedup vs baseline: 2.1097x; 1.0267x over previous
//
#include <hip/hip_runtime.h>

#define N_NODES 20000
#define HID 64
#define NSTEPS 6
#define NSLICE 8
#define SLICE_SZ (N_NODES / NSLICE)  // 2500
#define SUBB 64                      // sub-chunks per slice (phase 2)
#define NBLK (NSLICE * SUBB)         // 512 blocks for hist/scatter
#define NB1 512                      // blocks for count/bucket phase
#define MAGIC 13422                  // floor(d*13422 / 2^25) == d/2500 for d < 20000

typedef _Float16 h2_t __attribute__((ext_vector_type(2)));

union U16H { unsigned short u; _Float16 h; };
union U32H2 { int i; h2_t v; };

__device__ __forceinline__ h2_t int_as_h2(int i) { U32H2 u; u.i = i; return u.v; }
__device__ __forceinline__ _Float16 us_as_h(unsigned short s) { U16H u; u.u = s; return u.h; }
__device__ __forceinline__ unsigned short h_as_us(_Float16 h) { U16H u; u.h = h; return u.u; }

#if __has_builtin(__builtin_amdgcn_fdot2)
#define FDOT2(a, b, c) __builtin_amdgcn_fdot2((a), (b), (c), false)
#else
__device__ __forceinline__ float FDOT2(h2_t a, h2_t b, float c) {
    return fmaf((float)a.x, (float)b.x, fmaf((float)a.y, (float)b.y, c));
}
#endif

__device__ __forceinline__ int slice_of(int d) {
    return (int)(((unsigned)d * (unsigned)MAGIC) >> 25);
}
__device__ __forceinline__ float softplusf_(float x) {
    return (x > 0.f) ? (x + log1pf(expf(-x))) : log1pf(expf(x));
}
__device__ __forceinline__ float sigmoidf_(float x) {
    return 1.f / (1.f + expf(-x));
}

// ---------------- prep: tiny per-call constants ----------------
__global__ __launch_bounds__(64) void prep_kernel(const float* __restrict__ g_logits,
                                                  const float* __restrict__ alpha_logits,
                                                  const int* __restrict__ cell_idx,
                                                  const float* __restrict__ cell_emb,
                                                  const float* __restrict__ W2,
                                                  const float* __restrict__ b2,
                                                  float* __restrict__ gsign,
                                                  float* __restrict__ alph,
                                                  float* __restrict__ cell_dot) {
    int t = threadIdx.x;
    if (t < 6) gsign[t] = ((t & 1) ? -1.f : 1.f) * softplusf_(g_logits[t]);
    if (t < NSTEPS) alph[t] = sigmoidf_(alpha_logits[t]);
    int ci = cell_idx[t];
    float acc = b2[0];
    for (int hh = 0; hh < HID; ++hh) acc = fmaf(cell_emb[ci * HID + hh], W2[hh], acc);
    cell_dot[t] = acc;
}

// ---------------- P0: per-(block,slice) edge counts (read edges ONCE) ----------------
__global__ __launch_bounds__(256) void count8_kernel(const int* __restrict__ edst,
                                                     int* __restrict__ gcnt, int TE) {
    __shared__ int lh[8];
    int bk = blockIdx.x;
    int lane = threadIdx.x & 63;
    if (threadIdx.x < 8) lh[threadIdx.x] = 0;
    __syncthreads();
    int chunk = ((TE + NB1 - 1) / NB1 + 255) & ~255;
    int lo = bk * chunk;
    int hi = min(lo + chunk, TE);
    int my = 0;
    for (int ii = 0; ii < chunk; ii += 256) {
        int i = lo + ii + (int)threadIdx.x;
        bool act = i < hi;
        int s = -1;
        if (act) s = slice_of(__builtin_nontemporal_load(edst + i));
#pragma unroll
        for (int q = 0; q < 8; ++q) {
            unsigned long long b = __ballot(s == q);
            if (lane == q) my += (int)__popcll(b);
        }
    }
    if (lane < 8) atomicAdd(&lh[lane], my);
    __syncthreads();
    if (threadIdx.x < 8) gcnt[bk * 8 + threadIdx.x] = lh[threadIdx.x];
}

// ---------------- P0b: scan gcnt -> blkoff + bbase[9] ----------------
__global__ __launch_bounds__(256) void scan8_kernel(const int* __restrict__ gcnt,
                                                    int* __restrict__ blkoff,
                                                    int* __restrict__ bbase) {
    __shared__ int psum[8][33];
    int tid = threadIdx.x;
    int s = tid >> 5, g = tid & 31;
    const int per = NB1 / 32;  // 16
    int sum = 0;
    for (int b = g * per; b < (g + 1) * per; ++b) sum += gcnt[b * 8 + s];
    psum[s][g] = sum;
    __syncthreads();
    if (tid < 8) {
        int run = 0;
        for (int i = 0; i < 32; ++i) { int v = psum[tid][i]; psum[tid][i] = run; run += v; }
        psum[tid][32] = run;
    }
    __syncthreads();
    int run = psum[s][g];
    for (int b = g * per; b < (g + 1) * per; ++b) {
        blkoff[b * 8 + s] = run;
        run += gcnt[b * 8 + s];
    }
    if (tid == 0) {
        int acc = 0;
        bbase[0] = 0;
        for (int q = 0; q < 8; ++q) { acc += psum[q][32]; bbase[q + 1] = acc; }
    }
}

// ---------------- P1: bucket edges by slice; pack {src | dl<<16, coef_f32} ----------------
__global__ __launch_bounds__(256) void bucket_kernel(const int* __restrict__ esrc,
                                                     const int* __restrict__ edst,
                                                     const float* __restrict__ eval,
                                                     const float* __restrict__ gsign,
                                                     const int* __restrict__ blkoff,
                                                     const int* __restrict__ bbase,
                                                     int2* __restrict__ bucket,
                                                     int E, int TE) {
    __shared__ int lcur[8];
    int bk = blockIdx.x;
    int lane = threadIdx.x & 63;
    if (threadIdx.x < 8) lcur[threadIdx.x] = bbase[threadIdx.x] + blkoff[bk * 8 + threadIdx.x];
    __syncthreads();
    int chunk = ((TE + NB1 - 1) / NB1 + 255) & ~255;
    int lo = bk * chunk;
    int hi = min(lo + chunk, TE);
    for (int ii = 0; ii < chunk; ii += 256) {
        int i = lo + ii + (int)threadIdx.x;
        bool act = i < hi;
        int s = -1, meta = 0, cb = 0;
        if (act) {
            int d  = __builtin_nontemporal_load(edst + i);
            int sv = __builtin_nontemporal_load(esrc + i);
            float ev = __builtin_nontemporal_load(eval + i);
            s = slice_of(d);
            int dl = d - s * SLICE_SZ;
            meta = sv | (dl << 16);
            int r = (i >= E) + (i >= 2 * E) + (i >= 3 * E) + (i >= 4 * E) + (i >= 5 * E);
            cb = __float_as_int(gsign[r] * ev);
        }
        int pos = 0;
#pragma unroll
        for (int q = 0; q < 8; ++q) {
            unsigned long long b = __ballot(s == q);
            if (b) {
                int leader = (int)__ffsll(b) - 1;
                int base = 0;
                if (lane == leader) base = atomicAdd(&lcur[q], (int)__popcll(b));
                base = __shfl(base, leader);
                if (s == q) pos = base + (int)__popcll(b & ((1ull << lane) - 1ull));
            }
        }
        if (act) bucket[pos] = make_int2(meta, cb);
    }
}

// ---------------- P2: per-(slice,sub) LDS histogram from the bucket ----------------
__global__ __launch_bounds__(256) void hist2db_kernel(const int2* __restrict__ bucket,
                                                      const int* __restrict__ bbase,
                                                      int* __restrict__ blkcnt) {
    __shared__ int lh[SLICE_SZ];
    int bk = blockIdx.x;
    int slice = bk & (NSLICE - 1);
    int sub = bk >> 3;
    for (int b = threadIdx.x; b < SLICE_SZ; b += 256) lh[b] = 0;
    __syncthreads();
    int lo = bbase[slice];
    int total = bbase[slice + 1] - lo;
    int chunk = ((total + SUBB - 1) / SUBB + 255) & ~255;
    int beg = lo + sub * chunk;
    int end = min(beg + chunk, lo + total);
    const int* mp = (const int*)bucket;
    for (int i = beg + (int)threadIdx.x; i < end; i += 256) {
        int meta = __builtin_nontemporal_load(mp + 2 * (size_t)i);
        atomicAdd(&lh[((unsigned)meta) >> 16], 1);
    }
    __syncthreads();
    int* out = blkcnt + (size_t)(slice * SUBB + sub) * SLICE_SZ;
    for (int b = threadIdx.x; b < SLICE_SZ; b += 256) out[b] = lh[b];
}

// ---------------- P3a: per-bin exclusive prefix across sub-blocks ----------------
__global__ __launch_bounds__(256) void colscan_kernel(int* __restrict__ blkcnt,
                                                      int* __restrict__ counts) {
    int n = blockIdx.x * 256 + threadIdx.x;
    if (n >= N_NODES) return;
    int slice = n / SLICE_SZ, bin = n % SLICE_SZ;
    size_t base = (size_t)slice * SUBB * SLICE_SZ + bin;
    int run = 0;
#pragma unroll 8
    for (int s = 0; s < SUBB; ++s) {
        size_t idx = base + (size_t)s * SLICE_SZ;
        int t = blkcnt[idx];
        blkcnt[idx] = run;
        run += t;
    }
    counts[n] = run;
}

// ---------------- P3b: row_ptr from counts ----------------
__global__ __launch_bounds__(256) void scan_kernel(const int* __restrict__ counts,
                                                   int* __restrict__ row_ptr, int n) {
    __shared__ int sums[256];
    int tid = threadIdx.x;
    int seg = (n + 255) >> 8;
    int beg = tid * seg;
    int end = min(beg + seg, n);
    int s = 0;
    for (int i = beg; i < end; ++i) s += counts[i];
    sums[tid] = s;
    __syncthreads();
    if (tid == 0) {
        int run = 0;
        for (int i = 0; i < 256; ++i) { int v = sums[i]; sums[i] = run; run += v; }
        row_ptr[n] = run;
    }
    __syncthreads();
    int off = sums[tid];
    for (int i = beg; i < end; ++i) {
        row_ptr[i] = off;
        off += counts[i];
    }
}

// ---------------- P4: placement into grouped-4 entries ----------------
// Entry group g (16B): [src0..src3 : u16×4][c0,c1 : f16×2][c2,c3 : f16×2]
__global__ __launch_bounds__(256) void scatter2b_kernel(const int2* __restrict__ bucket,
                                                        const int* __restrict__ bbase,
                                                        const int* __restrict__ row_ptr,
                                                        const int* __restrict__ blkcnt,
                                                        unsigned short* __restrict__ entries) {
    __shared__ int lbase[SLICE_SZ];
    int bk = blockIdx.x;
    int slice = bk & (NSLICE - 1);
    int sub = bk >> 3;
    int lo_n = slice * SLICE_SZ;
    const int* boff = blkcnt + (size_t)(slice * SUBB + sub) * SLICE_SZ;
    for (int b = threadIdx.x; b < SLICE_SZ; b += 256) lbase[b] = row_ptr[lo_n + b] + boff[b];
    __syncthreads();
    int lo = bbase[slice];
    int total = bbase[slice + 1] - lo;
    int chunk = ((total + SUBB - 1) / SUBB + 255) & ~255;
    int beg = lo + sub * chunk;
    int end = min(beg + chunk, lo + total);
    for (int i = beg + (int)threadIdx.x; i < end; i += 256) {
        long long rec = __builtin_nontemporal_load((const long long*)bucket + i);
        int meta = (int)rec;
        float cf = __int_as_float((int)(rec >> 32));
        int pos = atomicAdd(&lbase[((unsigned)meta) >> 16], 1);
        int g = pos >> 2, sl = pos & 3;
        entries[(size_t)g * 8 + sl]     = (unsigned short)(meta & 0xFFFF);
        entries[(size_t)g * 8 + 4 + sl] = h_as_us((_Float16)cf);
    }
}

// ---------------- transpose (64-tile), optional f16 side output ----------------
__global__ __launch_bounds__(256) void transpose64(float* __restrict__ out,
                                                   _Float16* __restrict__ outh,
                                                   const float* __restrict__ in,
                                                   int R, int C) {
    __shared__ float tile[64][65];
    int c0 = blockIdx.x * 64, r0 = blockIdx.y * 64;
    int tx = threadIdx.x & 63, ty = threadIdx.x >> 6;
#pragma unroll
    for (int i = 0; i < 16; ++i) {
        int r = r0 + ty + i * 4;
        int c = c0 + tx;
        tile[ty + i * 4][tx] = (r < R && c < C) ? in[(size_t)r * C + c] : 0.f;
    }
    __syncthreads();
#pragma unroll
    for (int i = 0; i < 16; ++i) {
        int c = c0 + ty + i * 4;
        int r = r0 + tx;
        if (c < C && r < R) {
            float v = tile[tx][ty + i * 4];
            out[(size_t)c * R + r] = v;
            if (outh) outh[(size_t)c * R + r] = (_Float16)v;
        }
    }
}

// ---------------- propagation step (f16 gathers, dot2, fp32 accumulate) ----------------
__global__ __launch_bounds__(256) void step_kernel(const _Float16* __restrict__ h_in,
                                                   const float* __restrict__ h0,
                                                   _Float16* __restrict__ h_out,
                                                   float* __restrict__ hF,
                                                   const int* __restrict__ row_ptr,
                                                   const int4* __restrict__ ep4,
                                                   const float* __restrict__ alph,
                                                   int k, int last) {
    int lane = threadIdx.x & 63;
    int node = blockIdx.x * 4 + (threadIdx.x >> 6);
    if (node >= N_NODES) return;
    int beg = __builtin_amdgcn_readfirstlane(row_ptr[node]);
    int end = __builtin_amdgcn_readfirstlane(row_ptr[node + 1]);
    const unsigned short* sp = (const unsigned short*)ep4;
    float a0 = 0.f, a1 = 0.f, a2 = 0.f, a3 = 0.f;
    int e = beg;
    // head peel to 4-alignment
    while ((e & 3) && e < end) {
        int g = e >> 2, sl = e & 3;
        unsigned src = sp[(size_t)g * 8 + sl];
        float cf = (float)us_as_h(sp[(size_t)g * 8 + 4 + sl]);
        a0 = fmaf(cf, (float)h_in[src * 64 + lane], a0);
        ++e;
    }
    for (; e + 16 <= end; e += 16) {
        int g = e >> 2;
        int4 q0 = ep4[g], q1 = ep4[g + 1], q2 = ep4[g + 2], q3 = ep4[g + 3];
        h2_t hv[8];
        unsigned s;
        s = (unsigned)q0.x; hv[0].x = h_in[(s & 0xffffu) * 64 + lane]; hv[0].y = h_in[(s >> 16) * 64 + lane];
        s = (unsigned)q0.y; hv[1].x = h_in[(s & 0xffffu) * 64 + lane]; hv[1].y = h_in[(s >> 16) * 64 + lane];
        s = (unsigned)q1.x; hv[2].x = h_in[(s & 0xffffu) * 64 + lane]; hv[2].y = h_in[(s >> 16) * 64 + lane];
        s = (unsigned)q1.y; hv[3].x = h_in[(s & 0xffffu) * 64 + lane]; hv[3].y = h_in[(s >> 16) * 64 + lane];
        s = (unsigned)q2.x; hv[4].x = h_in[(s & 0xffffu) * 64 + lane]; hv[4].y = h_in[(s >> 16) * 64 + lane];
        s = (unsigned)q2.y; hv[5].x = h_in[(s & 0xffffu) * 64 + lane]; hv[5].y = h_in[(s >> 16) * 64 + lane];
        s = (unsigned)q3.x; hv[6].x = h_in[(s & 0xffffu) * 64 + lane]; hv[6].y = h_in[(s >> 16) * 64 + lane];
        s = (unsigned)q3.y; hv[7].x = h_in[(s & 0xffffu) * 64 + lane]; hv[7].y = h_in[(s >> 16) * 64 + lane];
        a0 = FDOT2(hv[0], int_as_h2(q0.z), a0);
        a1 = FDOT2(hv[1], int_as_h2(q0.w), a1);
        a2 = FDOT2(hv[2], int_as_h2(q1.z), a2);
        a3 = FDOT2(hv[3], int_as_h2(q1.w), a3);
        a0 = FDOT2(hv[4], int_as_h2(q2.z), a0);
        a1 = FDOT2(hv[5], int_as_h2(q2.w), a1);
        a2 = FDOT2(hv[6], int_as_h2(q3.z), a2);
        a3 = FDOT2(hv[7], int_as_h2(q3.w), a3);
    }
    for (; e + 4 <= end; e += 4) {
        int4 q = ep4[e >> 2];
        h2_t v0, v1;
        unsigned s;
        s = (unsigned)q.x; v0.x = h_in[(s & 0xffffu) * 64 + lane]; v0.y = h_in[(s >> 16) * 64 + lane];
        s = (unsigned)q.y; v1.x = h_in[(s & 0xffffu) * 64 + lane]; v1.y = h_in[(s >> 16) * 64 + lane];
        a0 = FDOT2(v0, int_as_h2(q.z), a0);
        a1 = FDOT2(v1, int_as_h2(q.w), a1);
    }
    while (e < end) {
        int g = e >> 2, sl = e & 3;
        unsigned src = sp[(size_t)g * 8 + sl];
        float cf = (float)us_as_h(sp[(size_t)g * 8 + 4 + sl]);
        a2 = fmaf(cf, (float)h_in[src * 64 + lane], a2);
        ++e;
    }
    float a = alph[k];
    int idx = node * 64 + lane;
    float r = fmaf(a, h0[idx], (1.f - a) * ((a0 + a1) + (a2 + a3)));
    if (last) hF[idx] = r;
    else h_out[idx] = (_Float16)r;
}

// ---------------- decode ----------------
__global__ __launch_bounds__(256) void decode_kernel(float* __restrict__ y,
                                                     const float* __restrict__ ctl,
                                                     const float* __restrict__ u,
                                                     const float* __restrict__ h_bn,
                                                     const float* __restrict__ W1,
                                                     const float* __restrict__ b1,
                                                     const float* __restrict__ W2,
                                                     const float* __restrict__ cell_dot,
                                                     int total) {
    __shared__ float4 pack[HID];
    __shared__ float w2s[HID];
    if (threadIdx.x < HID) {
        int hh = threadIdx.x;
        pack[hh] = make_float4(W1[0 * HID + hh], W1[1 * HID + hh], W1[2 * HID + hh], b1[hh]);
        w2s[hh] = W2[hh];
    }
    __syncthreads();
    int idx = blockIdx.x * 256 + threadIdx.x;
    if (idx >= total) return;
    int b = idx / N_NODES;
    float xc = ctl[idx], xu = u[idx], xh = h_bn[idx];
    float acc = 0.f;
#pragma unroll 8
    for (int hh = 0; hh < HID; ++hh) {
        float4 p = pack[hh];
        float t = fmaf(xc, p.x, fmaf(xu, p.y, fmaf(xh, p.z, p.w)));
        t = fmaxf(t, 0.f);
        acc = fmaf(t, w2s[hh], acc);
    }
    y[idx] = acc + cell_dot[b];
}

// ---------------- launch ----------------
extern "C" void kernel_launch(void* const* d_in, const int* in_sizes, int n_in,
                              void* d_out, int out_size, void* d_ws, size_t ws_size,
                              hipStream_t stream) {
    const float* ctl          = (const float*)d_in[0];
    const float* u_raw        = (const float*)d_in[1];
    const int*   cell_idx     = (const int*)d_in[2];
    const int*   edge_src     = (const int*)d_in[3];
    const int*   edge_dst     = (const int*)d_in[4];
    const float* edge_val     = (const float*)d_in[5];
    const float* g_logits     = (const float*)d_in[6];
    const float* alpha_logits = (const float*)d_in[7];
    const float* cell_emb     = (const float*)d_in[8];
    const float* W1           = (const float*)d_in[9];
    const float* b1           = (const float*)d_in[10];
    const float* W2           = (const float*)d_in[11];
    const float* b2           = (const float*)d_in[12];
    float* y = (float*)d_out;

    const int TE = in_sizes[3];   // 6 * E
    const int E  = TE / 6;
    const int NB = N_NODES * 64;  // h elements

    char* ws = (char*)d_ws;
    size_t off = 0;
    auto alloc = [&](size_t bytes) -> char* {
        char* p = ws + off;
        off += (bytes + 255) & ~(size_t)255;
        return p;
    };
    int* row_ptr = (int*)alloc((N_NODES + 1) * sizeof(int));
    int* counts  = (int*)alloc(N_NODES * sizeof(int));
    int* blkcnt  = (int*)alloc((size_t)NSLICE * SUBB * SLICE_SZ * sizeof(int));
    int* gcnt    = (int*)alloc((size_t)NB1 * 8 * sizeof(int));
    int* blkoff  = (int*)alloc((size_t)NB1 * 8 * sizeof(int));
    int* bbase   = (int*)alloc(16 * sizeof(int));
    unsigned short* entries = (unsigned short*)alloc(((size_t)TE / 4 + 2) * 16);
    // overlay: bucket (build) then h buffers (propagate) — stream-serialized
    size_t need_h = (size_t)NB * (2 + 2 + 2 + 4 + 4);
    size_t ov_sz = (size_t)TE * sizeof(int2);
    if (ov_sz < need_h) ov_sz = need_h;
    char* overlay = alloc(ov_sz);
    float* u_t      = (float*)alloc((size_t)NB * sizeof(float));
    float* gsign    = (float*)alloc(8 * sizeof(float));
    float* alph     = (float*)alloc(8 * sizeof(float));
    float* cell_dot = (float*)alloc(64 * sizeof(float));

    int2* bucket = (int2*)overlay;
    _Float16* uh  = (_Float16*)overlay;                      // NB*2
    _Float16* hA  = (_Float16*)(overlay + (size_t)NB * 2);   // NB*2
    _Float16* hB  = (_Float16*)(overlay + (size_t)NB * 4);   // NB*2
    float* hF   = (float*)(overlay + (size_t)NB * 6);        // NB*4
    float* h_bn = (float*)(overlay + (size_t)NB * 10);       // NB*4

    // 0. tiny per-call constants
    prep_kernel<<<1, 64, 0, stream>>>(g_logits, alpha_logits, cell_idx, cell_emb,
                                      W2, b2, gsign, alph, cell_dot);

    // 1. CSR build — edges read once, zero global atomics, XCD-local placement
    count8_kernel<<<NB1, 256, 0, stream>>>(edge_dst, gcnt, TE);
    scan8_kernel<<<1, 256, 0, stream>>>(gcnt, blkoff, bbase);
    bucket_kernel<<<NB1, 256, 0, stream>>>(edge_src, edge_dst, edge_val, gsign,
                                           blkoff, bbase, bucket, E, TE);
    hist2db_kernel<<<NBLK, 256, 0, stream>>>(bucket, bbase, blkcnt);
    colscan_kernel<<<(N_NODES + 255) / 256, 256, 0, stream>>>(blkcnt, counts);
    scan_kernel<<<1, 256, 0, stream>>>(counts, row_ptr, N_NODES);
    scatter2b_kernel<<<NBLK, 256, 0, stream>>>(bucket, bbase, row_ptr, blkcnt, entries);

    // 2. u_raw [B,N] -> u_t [N,B] (fp32) + uh (f16)   [bucket dead after scatter]
    transpose64<<<dim3((N_NODES + 63) / 64, 1), 256, 0, stream>>>(u_t, uh, u_raw,
                                                                  64, N_NODES);

    // 3. 6 propagation steps: f16 ping-pong, fp32 final into hF
    const _Float16* hin = uh;
    for (int k = 0; k < NSTEPS; ++k) {
        _Float16* hout = (k & 1) ? hB : hA;
        step_kernel<<<(N_NODES + 3) / 4, 256, 0, stream>>>(hin, u_t, hout, hF, row_ptr,
                                                           (const int4*)entries, alph,
                                                           k, k == NSTEPS - 1);
        hin = hout;
    }

    // 4. hF [N,64] -> h_bn [B,N]
    transpose64<<<dim3(1, (N_NODES + 63) / 64), 256, 0, stream>>>(h_bn, (_Float16*)0,
                                                                  hF, N_NODES, 64);

    // 5. decode
    decode_kernel<<<(out_size + 255) / 256, 256, 0, stream>>>(y, ctl, u_raw, h_bn,
                                                              W1, b1, W2, cell_dot, out_size);
}

// Round 6
// 398.443 us; speedup vs baseline: 2.3326x; 1.1056x over previous
//
#include <hip/hip_runtime.h>

#define N_NODES 20000
#define HID 64
#define NSTEPS 6
#define NSLICE 8
#define SLICE_SZ (N_NODES / NSLICE)  // 2500
#define SUBB 64                      // sub-chunks per slice (phase 2)
#define NBLK (NSLICE * SUBB)         // 512 blocks for hist/scatter
#define NB1 512                      // blocks for count/bucket phase
#define MAGIC 13422                  // floor(d*13422 / 2^25) == d/2500 for d < 20000

union U16H { unsigned short u; _Float16 h; };
union U4H8 { uint4 u; _Float16 h[8]; };

__device__ __forceinline__ _Float16 us_as_h(unsigned short s) { U16H u; u.u = s; return u.h; }
__device__ __forceinline__ unsigned short h_as_us(_Float16 h) { U16H u; u.h = h; return u.u; }

__device__ __forceinline__ int slice_of(int d) {
    return (int)(((unsigned)d * (unsigned)MAGIC) >> 25);
}
__device__ __forceinline__ float softplusf_(float x) {
    return (x > 0.f) ? (x + log1pf(expf(-x))) : log1pf(expf(x));
}
__device__ __forceinline__ float sigmoidf_(float x) {
    return 1.f / (1.f + expf(-x));
}

// ---------------- prep: tiny per-call constants ----------------
__global__ __launch_bounds__(64) void prep_kernel(const float* __restrict__ g_logits,
                                                  const float* __restrict__ alpha_logits,
                                                  const int* __restrict__ cell_idx,
                                                  const float* __restrict__ cell_emb,
                                                  const float* __restrict__ W2,
                                                  const float* __restrict__ b2,
                                                  float* __restrict__ gsign,
                                                  float* __restrict__ alph,
                                                  float* __restrict__ cell_dot) {
    int t = threadIdx.x;
    if (t < 6) gsign[t] = ((t & 1) ? -1.f : 1.f) * softplusf_(g_logits[t]);
    if (t < NSTEPS) alph[t] = sigmoidf_(alpha_logits[t]);
    int ci = cell_idx[t];
    float acc = b2[0];
    for (int hh = 0; hh < HID; ++hh) acc = fmaf(cell_emb[ci * HID + hh], W2[hh], acc);
    cell_dot[t] = acc;
}

// ---------------- P0: per-(block,slice) edge counts (read edges ONCE) ----------------
__global__ __launch_bounds__(256) void count8_kernel(const int* __restrict__ edst,
                                                     int* __restrict__ gcnt, int TE) {
    __shared__ int lh[8];
    int bk = blockIdx.x;
    int lane = threadIdx.x & 63;
    if (threadIdx.x < 8) lh[threadIdx.x] = 0;
    __syncthreads();
    int chunk = ((TE + NB1 - 1) / NB1 + 255) & ~255;
    int lo = bk * chunk;
    int hi = min(lo + chunk, TE);
    int my = 0;
    for (int ii = 0; ii < chunk; ii += 256) {
        int i = lo + ii + (int)threadIdx.x;
        bool act = i < hi;
        int s = -1;
        if (act) s = slice_of(__builtin_nontemporal_load(edst + i));
#pragma unroll
        for (int q = 0; q < 8; ++q) {
            unsigned long long b = __ballot(s == q);
            if (lane == q) my += (int)__popcll(b);
        }
    }
    if (lane < 8) atomicAdd(&lh[lane], my);
    __syncthreads();
    if (threadIdx.x < 8) gcnt[bk * 8 + threadIdx.x] = lh[threadIdx.x];
}

// ---------------- P0b: scan gcnt -> blkoff + bbase[9] ----------------
__global__ __launch_bounds__(256) void scan8_kernel(const int* __restrict__ gcnt,
                                                    int* __restrict__ blkoff,
                                                    int* __restrict__ bbase) {
    __shared__ int psum[8][33];
    int tid = threadIdx.x;
    int s = tid >> 5, g = tid & 31;
    const int per = NB1 / 32;  // 16
    int sum = 0;
    for (int b = g * per; b < (g + 1) * per; ++b) sum += gcnt[b * 8 + s];
    psum[s][g] = sum;
    __syncthreads();
    if (tid < 8) {
        int run = 0;
        for (int i = 0; i < 32; ++i) { int v = psum[tid][i]; psum[tid][i] = run; run += v; }
        psum[tid][32] = run;
    }
    __syncthreads();
    int run = psum[s][g];
    for (int b = g * per; b < (g + 1) * per; ++b) {
        blkoff[b * 8 + s] = run;
        run += gcnt[b * 8 + s];
    }
    if (tid == 0) {
        int acc = 0;
        bbase[0] = 0;
        for (int q = 0; q < 8; ++q) { acc += psum[q][32]; bbase[q + 1] = acc; }
    }
}

// ---------------- P1: bucket edges by slice; pack {src | dl<<16, coef_f32} ----------------
__global__ __launch_bounds__(256) void bucket_kernel(const int* __restrict__ esrc,
                                                     const int* __restrict__ edst,
                                                     const float* __restrict__ eval,
                                                     const float* __restrict__ gsign,
                                                     const int* __restrict__ blkoff,
                                                     const int* __restrict__ bbase,
                                                     int2* __restrict__ bucket,
                                                     int E, int TE) {
    __shared__ int lcur[8];
    int bk = blockIdx.x;
    int lane = threadIdx.x & 63;
    if (threadIdx.x < 8) lcur[threadIdx.x] = bbase[threadIdx.x] + blkoff[bk * 8 + threadIdx.x];
    __syncthreads();
    int chunk = ((TE + NB1 - 1) / NB1 + 255) & ~255;
    int lo = bk * chunk;
    int hi = min(lo + chunk, TE);
    for (int ii = 0; ii < chunk; ii += 256) {
        int i = lo + ii + (int)threadIdx.x;
        bool act = i < hi;
        int s = -1, meta = 0, cb = 0;
        if (act) {
            int d  = __builtin_nontemporal_load(edst + i);
            int sv = __builtin_nontemporal_load(esrc + i);
            float ev = __builtin_nontemporal_load(eval + i);
            s = slice_of(d);
            int dl = d - s * SLICE_SZ;
            meta = sv | (dl << 16);
            int r = (i >= E) + (i >= 2 * E) + (i >= 3 * E) + (i >= 4 * E) + (i >= 5 * E);
            cb = __float_as_int(gsign[r] * ev);
        }
        int pos = 0;
#pragma unroll
        for (int q = 0; q < 8; ++q) {
            unsigned long long b = __ballot(s == q);
            if (b) {
                int leader = (int)__ffsll(b) - 1;
                int base = 0;
                if (lane == leader) base = atomicAdd(&lcur[q], (int)__popcll(b));
                base = __shfl(base, leader);
                if (s == q) pos = base + (int)__popcll(b & ((1ull << lane) - 1ull));
            }
        }
        if (act) bucket[pos] = make_int2(meta, cb);
    }
}

// ---------------- P2: per-(slice,sub) LDS histogram from the bucket ----------------
__global__ __launch_bounds__(256) void hist2db_kernel(const int2* __restrict__ bucket,
                                                      const int* __restrict__ bbase,
                                                      int* __restrict__ blkcnt) {
    __shared__ int lh[SLICE_SZ];
    int bk = blockIdx.x;
    int slice = bk & (NSLICE - 1);
    int sub = bk >> 3;
    for (int b = threadIdx.x; b < SLICE_SZ; b += 256) lh[b] = 0;
    __syncthreads();
    int lo = bbase[slice];
    int total = bbase[slice + 1] - lo;
    int chunk = ((total + SUBB - 1) / SUBB + 255) & ~255;
    int beg = lo + sub * chunk;
    int end = min(beg + chunk, lo + total);
    const int* mp = (const int*)bucket;
    for (int i = beg + (int)threadIdx.x; i < end; i += 256) {
        int meta = __builtin_nontemporal_load(mp + 2 * (size_t)i);
        atomicAdd(&lh[((unsigned)meta) >> 16], 1);
    }
    __syncthreads();
    int* out = blkcnt + (size_t)(slice * SUBB + sub) * SLICE_SZ;
    for (int b = threadIdx.x; b < SLICE_SZ; b += 256) out[b] = lh[b];
}

// ---------------- P3a: per-bin exclusive prefix across sub-blocks ----------------
__global__ __launch_bounds__(256) void colscan_kernel(int* __restrict__ blkcnt,
                                                      int* __restrict__ counts) {
    int n = blockIdx.x * 256 + threadIdx.x;
    if (n >= N_NODES) return;
    int slice = n / SLICE_SZ, bin = n % SLICE_SZ;
    size_t base = (size_t)slice * SUBB * SLICE_SZ + bin;
    int run = 0;
#pragma unroll 8
    for (int s = 0; s < SUBB; ++s) {
        size_t idx = base + (size_t)s * SLICE_SZ;
        int t = blkcnt[idx];
        blkcnt[idx] = run;
        run += t;
    }
    counts[n] = run;
}

// ---------------- P3b: grp_ptr from counts (rows padded to multiples of 8) ----------------
__global__ __launch_bounds__(256) void scan_kernel(const int* __restrict__ counts,
                                                   int* __restrict__ grp_ptr, int n) {
    __shared__ int sums[256];
    int tid = threadIdx.x;
    int seg = (n + 255) >> 8;
    int beg = tid * seg;
    int end = min(beg + seg, n);
    int s = 0;
    for (int i = beg; i < end; ++i) s += (counts[i] + 7) >> 3;
    sums[tid] = s;
    __syncthreads();
    if (tid == 0) {
        int run = 0;
        for (int i = 0; i < 256; ++i) { int v = sums[i]; sums[i] = run; run += v; }
        grp_ptr[n] = run;
    }
    __syncthreads();
    int off = sums[tid];
    for (int i = beg; i < end; ++i) {
        grp_ptr[i] = off;
        off += (counts[i] + 7) >> 3;
    }
}

// ---------------- P4: placement into 8-edge groups ----------------
// Group g: eg[8g + s] = src | (coef_f16 << 16), s=0..7. Pad slots stay 0 (memset).
__global__ __launch_bounds__(256) void scatter2b_kernel(const int2* __restrict__ bucket,
                                                        const int* __restrict__ bbase,
                                                        const int* __restrict__ grp_ptr,
                                                        const int* __restrict__ blkcnt,
                                                        unsigned* __restrict__ eg) {
    __shared__ int lbase[SLICE_SZ];
    int bk = blockIdx.x;
    int slice = bk & (NSLICE - 1);
    int sub = bk >> 3;
    int lo_n = slice * SLICE_SZ;
    const int* boff = blkcnt + (size_t)(slice * SUBB + sub) * SLICE_SZ;
    for (int b = threadIdx.x; b < SLICE_SZ; b += 256)
        lbase[b] = grp_ptr[lo_n + b] * 8 + boff[b];
    __syncthreads();
    int lo = bbase[slice];
    int total = bbase[slice + 1] - lo;
    int chunk = ((total + SUBB - 1) / SUBB + 255) & ~255;
    int beg = lo + sub * chunk;
    int end = min(beg + chunk, lo + total);
    for (int i = beg + (int)threadIdx.x; i < end; i += 256) {
        long long rec = __builtin_nontemporal_load((const long long*)bucket + i);
        int meta = (int)rec;
        float cf = __int_as_float((int)(rec >> 32));
        int pos = atomicAdd(&lbase[((unsigned)meta) >> 16], 1);
        eg[pos] = (unsigned)(meta & 0xFFFF) | ((unsigned)h_as_us((_Float16)cf) << 16);
    }
}

// ---------------- transpose (64-tile), optional f16 side output ----------------
__global__ __launch_bounds__(256) void transpose64(float* __restrict__ out,
                                                   _Float16* __restrict__ outh,
                                                   const float* __restrict__ in,
                                                   int R, int C) {
    __shared__ float tile[64][65];
    int c0 = blockIdx.x * 64, r0 = blockIdx.y * 64;
    int tx = threadIdx.x & 63, ty = threadIdx.x >> 6;
#pragma unroll
    for (int i = 0; i < 16; ++i) {
        int r = r0 + ty + i * 4;
        int c = c0 + tx;
        tile[ty + i * 4][tx] = (r < R && c < C) ? in[(size_t)r * C + c] : 0.f;
    }
    __syncthreads();
#pragma unroll
    for (int i = 0; i < 16; ++i) {
        int c = c0 + ty + i * 4;
        int r = r0 + tx;
        if (c < C && r < R) {
            float v = tile[tx][ty + i * 4];
            out[(size_t)c * R + r] = v;
            if (outh) outh[(size_t)c * R + r] = (_Float16)v;
        }
    }
}

// ---------------- propagation step: 8 edges per gather instruction ----------------
// Wave = 1 node. Lane L: edge (L>>3) of each group, batch octet (L&7)*8..+8.
// One dwordx4 gathers 8 f16 batches of one edge -> 8 edges per instruction/wave.
__global__ __launch_bounds__(256) void step_kernel(const _Float16* __restrict__ h_in,
                                                   const float* __restrict__ h0,
                                                   _Float16* __restrict__ h_out,
                                                   float* __restrict__ hF,
                                                   const int* __restrict__ grp_ptr,
                                                   const unsigned* __restrict__ eg,
                                                   const float* __restrict__ alph,
                                                   int k, int last) {
    int lane = threadIdx.x & 63;
    int node = blockIdx.x * 4 + (threadIdx.x >> 6);
    if (node >= N_NODES) return;
    int gb = __builtin_amdgcn_readfirstlane(grp_ptr[node]);
    int ge = __builtin_amdgcn_readfirstlane(grp_ptr[node + 1]);
    int sub8 = lane >> 3;                     // edge slot within group
    const _Float16* hbase = h_in + (lane & 7) * 8;  // batch-octet base
    float acc[8] = {0.f, 0.f, 0.f, 0.f, 0.f, 0.f, 0.f, 0.f};
    int g = gb;
    for (; g + 2 <= ge; g += 2) {
        unsigned e0 = eg[(size_t)g * 8 + sub8];
        unsigned e1 = eg[(size_t)(g + 1) * 8 + sub8];
        U4H8 v0, v1;
        v0.u = *(const uint4*)(hbase + (e0 & 0xFFFFu) * 64);
        v1.u = *(const uint4*)(hbase + (e1 & 0xFFFFu) * 64);
        float c0 = (float)us_as_h((unsigned short)(e0 >> 16));
        float c1 = (float)us_as_h((unsigned short)(e1 >> 16));
#pragma unroll
        for (int j = 0; j < 8; ++j) acc[j] = fmaf((float)v0.h[j], c0, acc[j]);
#pragma unroll
        for (int j = 0; j < 8; ++j) acc[j] = fmaf((float)v1.h[j], c1, acc[j]);
    }
    for (; g < ge; ++g) {
        unsigned e0 = eg[(size_t)g * 8 + sub8];
        U4H8 v0;
        v0.u = *(const uint4*)(hbase + (e0 & 0xFFFFu) * 64);
        float c0 = (float)us_as_h((unsigned short)(e0 >> 16));
#pragma unroll
        for (int j = 0; j < 8; ++j) acc[j] = fmaf((float)v0.h[j], c0, acc[j]);
    }
    // reduce the 8 edge-slots: lanes {c, c+8, ..., c+56} hold the same batch octet
#pragma unroll
    for (int st = 8; st < 64; st <<= 1) {
#pragma unroll
        for (int j = 0; j < 8; ++j) acc[j] += __shfl_xor(acc[j], st, 64);
    }
    if (lane < 8) {
        float a = alph[k];
        int base = node * 64 + lane * 8;
        float4 h0a = *(const float4*)(h0 + base);
        float4 h0b = *(const float4*)(h0 + base + 4);
        float om = 1.f - a;
        float r0 = fmaf(a, h0a.x, om * acc[0]);
        float r1 = fmaf(a, h0a.y, om * acc[1]);
        float r2 = fmaf(a, h0a.z, om * acc[2]);
        float r3 = fmaf(a, h0a.w, om * acc[3]);
        float r4 = fmaf(a, h0b.x, om * acc[4]);
        float r5 = fmaf(a, h0b.y, om * acc[5]);
        float r6 = fmaf(a, h0b.z, om * acc[6]);
        float r7 = fmaf(a, h0b.w, om * acc[7]);
        if (last) {
            *(float4*)(hF + base)     = make_float4(r0, r1, r2, r3);
            *(float4*)(hF + base + 4) = make_float4(r4, r5, r6, r7);
        } else {
            U4H8 o;
            o.h[0] = (_Float16)r0; o.h[1] = (_Float16)r1;
            o.h[2] = (_Float16)r2; o.h[3] = (_Float16)r3;
            o.h[4] = (_Float16)r4; o.h[5] = (_Float16)r5;
            o.h[6] = (_Float16)r6; o.h[7] = (_Float16)r7;
            *(uint4*)(h_out + base) = o.u;
        }
    }
}

// ---------------- decode ----------------
__global__ __launch_bounds__(256) void decode_kernel(float* __restrict__ y,
                                                     const float* __restrict__ ctl,
                                                     const float* __restrict__ u,
                                                     const float* __restrict__ h_bn,
                                                     const float* __restrict__ W1,
                                                     const float* __restrict__ b1,
                                                     const float* __restrict__ W2,
                                                     const float* __restrict__ cell_dot,
                                                     int total) {
    __shared__ float4 pack[HID];
    __shared__ float w2s[HID];
    if (threadIdx.x < HID) {
        int hh = threadIdx.x;
        pack[hh] = make_float4(W1[0 * HID + hh], W1[1 * HID + hh], W1[2 * HID + hh], b1[hh]);
        w2s[hh] = W2[hh];
    }
    __syncthreads();
    int idx = blockIdx.x * 256 + threadIdx.x;
    if (idx >= total) return;
    int b = idx / N_NODES;
    float xc = ctl[idx], xu = u[idx], xh = h_bn[idx];
    float acc = 0.f;
#pragma unroll 8
    for (int hh = 0; hh < HID; ++hh) {
        float4 p = pack[hh];
        float t = fmaf(xc, p.x, fmaf(xu, p.y, fmaf(xh, p.z, p.w)));
        t = fmaxf(t, 0.f);
        acc = fmaf(t, w2s[hh], acc);
    }
    y[idx] = acc + cell_dot[b];
}

// ---------------- launch ----------------
extern "C" void kernel_launch(void* const* d_in, const int* in_sizes, int n_in,
                              void* d_out, int out_size, void* d_ws, size_t ws_size,
                              hipStream_t stream) {
    const float* ctl          = (const float*)d_in[0];
    const float* u_raw        = (const float*)d_in[1];
    const int*   cell_idx     = (const int*)d_in[2];
    const int*   edge_src     = (const int*)d_in[3];
    const int*   edge_dst     = (const int*)d_in[4];
    const float* edge_val     = (const float*)d_in[5];
    const float* g_logits     = (const float*)d_in[6];
    const float* alpha_logits = (const float*)d_in[7];
    const float* cell_emb     = (const float*)d_in[8];
    const float* W1           = (const float*)d_in[9];
    const float* b1           = (const float*)d_in[10];
    const float* W2           = (const float*)d_in[11];
    const float* b2           = (const float*)d_in[12];
    float* y = (float*)d_out;

    const int TE = in_sizes[3];   // 6 * E
    const int E  = TE / 6;
    const int NB = N_NODES * 64;  // h elements

    char* ws = (char*)d_ws;
    size_t off = 0;
    auto alloc = [&](size_t bytes) -> char* {
        char* p = ws + off;
        off += (bytes + 255) & ~(size_t)255;
        return p;
    };
    int* grp_ptr = (int*)alloc((N_NODES + 1) * sizeof(int));
    int* counts  = (int*)alloc(N_NODES * sizeof(int));
    int* blkcnt  = (int*)alloc((size_t)NSLICE * SUBB * SLICE_SZ * sizeof(int));
    int* gcnt    = (int*)alloc((size_t)NB1 * 8 * sizeof(int));
    int* blkoff  = (int*)alloc((size_t)NB1 * 8 * sizeof(int));
    int* bbase   = (int*)alloc(16 * sizeof(int));
    const size_t MAXG = (size_t)TE / 8 + N_NODES + 8;            // padded group bound
    unsigned* eg = (unsigned*)alloc(MAXG * 8 * sizeof(unsigned)); // 32 B/group
    // overlay: bucket (build) then h buffers (propagate) — stream-serialized
    size_t need_h = (size_t)NB * (2 + 2 + 2 + 4 + 4);
    size_t ov_sz = (size_t)TE * sizeof(int2);
    if (ov_sz < need_h) ov_sz = need_h;
    char* overlay = alloc(ov_sz);
    float* u_t      = (float*)alloc((size_t)NB * sizeof(float));
    float* gsign    = (float*)alloc(8 * sizeof(float));
    float* alph     = (float*)alloc(8 * sizeof(float));
    float* cell_dot = (float*)alloc(64 * sizeof(float));

    int2* bucket = (int2*)overlay;
    _Float16* uh  = (_Float16*)overlay;                      // NB*2
    _Float16* hA  = (_Float16*)(overlay + (size_t)NB * 2);   // NB*2
    _Float16* hB  = (_Float16*)(overlay + (size_t)NB * 4);   // NB*2
    float* hF   = (float*)(overlay + (size_t)NB * 6);        // NB*4
    float* h_bn = (float*)(overlay + (size_t)NB * 10);       // NB*4

    // 0. tiny per-call constants; zero entry groups (pad slots must be {src=0,coef=0})
    prep_kernel<<<1, 64, 0, stream>>>(g_logits, alpha_logits, cell_idx, cell_emb,
                                      W2, b2, gsign, alph, cell_dot);
    hipMemsetAsync(eg, 0, MAXG * 8 * sizeof(unsigned), stream);

    // 1. CSR build — edges read once, zero global atomics, XCD-local placement
    count8_kernel<<<NB1, 256, 0, stream>>>(edge_dst, gcnt, TE);
    scan8_kernel<<<1, 256, 0, stream>>>(gcnt, blkoff, bbase);
    bucket_kernel<<<NB1, 256, 0, stream>>>(edge_src, edge_dst, edge_val, gsign,
                                           blkoff, bbase, bucket, E, TE);
    hist2db_kernel<<<NBLK, 256, 0, stream>>>(bucket, bbase, blkcnt);
    colscan_kernel<<<(N_NODES + 255) / 256, 256, 0, stream>>>(blkcnt, counts);
    scan_kernel<<<1, 256, 0, stream>>>(counts, grp_ptr, N_NODES);
    scatter2b_kernel<<<NBLK, 256, 0, stream>>>(bucket, bbase, grp_ptr, blkcnt, eg);

    // 2. u_raw [B,N] -> u_t [N,B] (fp32) + uh (f16)   [bucket dead after scatter]
    transpose64<<<dim3((N_NODES + 63) / 64, 1), 256, 0, stream>>>(u_t, uh, u_raw,
                                                                  64, N_NODES);

    // 3. 6 propagation steps: f16 ping-pong, fp32 final into hF
    const _Float16* hin = uh;
    for (int k = 0; k < NSTEPS; ++k) {
        _Float16* hout = (k & 1) ? hB : hA;
        step_kernel<<<(N_NODES + 3) / 4, 256, 0, stream>>>(hin, u_t, hout, hF, grp_ptr,
                                                           eg, alph, k, k == NSTEPS - 1);
        hin = hout;
    }

    // 4. hF [N,64] -> h_bn [B,N]
    transpose64<<<dim3(1, (N_NODES + 63) / 64), 256, 0, stream>>>(h_bn, (_Float16*)0,
                                                                  hF, N_NODES, 64);

    // 5. decode
    decode_kernel<<<(out_size + 255) / 256, 256, 0, stream>>>(y, ctl, u_raw, h_bn,
                                                              W1, b1, W2, cell_dot, out_size);
}